// Round 4
// baseline (2692.191 us; speedup 1.0000x reference)
//
#include <hip/hip_runtime.h>

#define NN 50000      // nodes
#define NE 800000     // edges
#define NGR 16        // graphs

typedef unsigned short u16;
typedef unsigned int u32;
typedef __attribute__((ext_vector_type(8))) short bf16x8;
typedef __attribute__((ext_vector_type(4))) float f32x4;

__device__ __forceinline__ u16 f2bf(float f) {       // RNE f32->bf16
  u32 u = __float_as_uint(f);
  return (u16)((u + 0x7fffu + ((u >> 16) & 1u)) >> 16);
}

// ---------- degree histogram ----------
__global__ void hist_deg(const int* col, int* deg) {
  int e = blockIdx.x * blockDim.x + threadIdx.x;
  if (e < NE) atomicAdd(&deg[col[e]], 1);
}

// ---------- per-graph counts (sorted ids) ----------
__device__ int lbound(const int* a, int n, int v) {
  int lo = 0, hi = n;
  while (lo < hi) { int m = (lo + hi) >> 1; if (a[m] < v) lo = m + 1; else hi = m; }
  return lo;
}
__global__ void count_graphs(const int* batch, const int* ebatch, int* cnt_n, int* cnt_e) {
  int t = threadIdx.x;
  if (t < NGR) cnt_n[t] = lbound(batch, NN, t + 1) - lbound(batch, NN, t);
  else if (t < 2 * NGR) { int g = t - NGR; cnt_e[g] = lbound(ebatch, NE, g + 1) - lbound(ebatch, NE, g); }
}

// ---------- exclusive scan of deg -> csr_off (single block) ----------
__global__ __launch_bounds__(256) void scan_deg(const int* deg, int* off) {
  __shared__ int sums[256];
  const int CH = (NN + 255) / 256;
  int t = threadIdx.x;
  int base = t * CH;
  int s = 0;
  for (int i = 0; i < CH; i++) { int idx = base + i; if (idx < NN) s += deg[idx]; }
  sums[t] = s;
  __syncthreads();
  for (int d = 1; d < 256; d <<= 1) {
    int v = (t >= d) ? sums[t - d] : 0;
    __syncthreads();
    sums[t] += v;
    __syncthreads();
  }
  int run = (t == 0) ? 0 : sums[t - 1];
  for (int i = 0; i < CH; i++) { int idx = base + i; if (idx < NN) { off[idx] = run; run += deg[idx]; } }
  if (t == 255) off[NN] = run;
}

// ---------- CSR fill ----------
__global__ void fill_csr(const int* col, const int* off, int* cursor, int* eid) {
  int e = blockIdx.x * blockDim.x + threadIdx.x;
  if (e < NE) {
    int c = col[e];
    int p = atomicAdd(&cursor[c], 1);
    eid[off[c] + p] = e;
  }
}

// ---------- weights f32 -> bf16 TRANSPOSED (W1T[l][n][k], W2T[l][n][k]) ----------
__global__ void prep_w_k(const float* W1, const float* W2, u16* W1T, u16* W2T) {
  int i = blockIdx.x * 256 + threadIdx.x;
  if (i < 3 * 128 * 128) {
    int l = i / 16384, k = (i >> 7) & 127, n = i & 127;
    W1T[l * 16384 + n * 128 + k] = f2bf(W1[i]);
  } else {
    int j = i - 3 * 128 * 128;
    if (j < 3 * 128 * 64) {
      int l = j / 8192, k = (j >> 6) & 127, n = j & 63;
      W2T[l * 8192 + n * 128 + k] = f2bf(W2[j]);
    }
  }
}

// ---------- h = CSR gather-mean of ea; pool h by batch -> gacc[g*256+loff+d] ----------
// Half-wave split: 32 lanes x float2 per row -> each load instr covers 2 edge
// rows; 4 explicit loads per iter = 8 rows in flight per wave.
__global__ __launch_bounds__(256) void gather_k(
    const float* __restrict__ ea, const int* __restrict__ off,
    const int* __restrict__ eid, const int* __restrict__ batch,
    float* __restrict__ hbuf, float* __restrict__ gacc,
    int loff, int store_h) {
  int gid = blockIdx.x * blockDim.x + threadIdx.x;
  int w = gid >> 6, lane = gid & 63;
  int nw = (gridDim.x * blockDim.x) >> 6;
  int h = lane >> 5, l = lane & 31;
  const float* base = ea + l * 2;      // float2 column base for this lane
  for (int n = w; n < NN; n += nw) {
    int s = off[n], e = off[n + 1];
    int g = batch[n];
    float a0x = 0.f, a0y = 0.f, a1x = 0.f, a1y = 0.f;
    float a2x = 0.f, a2y = 0.f, a3x = 0.f, a3y = 0.f;
    int i = s;
    for (; i + 8 <= e; i += 8) {       // 8 edges per iter, this half takes 4
      int e0 = eid[i + h];
      int e1 = eid[i + 2 + h];
      int e2 = eid[i + 4 + h];
      int e3 = eid[i + 6 + h];
      float2 v0 = *(const float2*)(base + (size_t)e0 * 64);
      float2 v1 = *(const float2*)(base + (size_t)e1 * 64);
      float2 v2 = *(const float2*)(base + (size_t)e2 * 64);
      float2 v3 = *(const float2*)(base + (size_t)e3 * 64);
      a0x += v0.x; a0y += v0.y;
      a1x += v1.x; a1y += v1.y;
      a2x += v2.x; a2y += v2.y;
      a3x += v3.x; a3y += v3.y;
    }
    for (; i + 2 <= e; i += 2) {       // pair tail
      int e0 = eid[i + h];
      float2 v = *(const float2*)(base + (size_t)e0 * 64);
      a0x += v.x; a0y += v.y;
    }
    if (i < e && h == 0) {             // single leftover edge
      int e0 = eid[i];
      float2 v = *(const float2*)(base + (size_t)e0 * 64);
      a0x += v.x; a0y += v.y;
    }
    float sx = (a0x + a1x) + (a2x + a3x);
    float sy = (a0y + a1y) + (a2y + a3y);
    sx += __shfl_xor(sx, 32);
    sy += __shfl_xor(sy, 32);
    if (h == 0) {
      float inv = 1.f / (float)max(e - s, 1);
      float hx = sx * inv, hy = sy * inv;
      if (store_h) {
        float2 hv = {hx, hy};
        *(float2*)(hbuf + (size_t)n * 64 + l * 2) = hv;
      }
      float* dst = gacc + g * 256 + loff + l * 2;
      atomicAdd(dst + 0, hx);
      atomicAdd(dst + 1, hy);
    }
  }
}

// ---------- edge MLP via bf16 MFMA: ea = relu([h[row],ea]@W1+b1)@W2+b2, in-place ----------
// Block = 256 thr (4 waves), 64 edges. Fused ge-pool epilogue for the OUTPUT
// rows, and (layer 0 only) fused ge-pool of the INPUT ea rows read during
// staging. Staging = pure load phase (8 float4 in flight) then process phase,
// so gacc atomics can't serialize the loads (all ptrs __restrict__).
__global__ __launch_bounds__(256) void mlp_mfma_k(
    const float* __restrict__ hbuf, float* __restrict__ ea,
    const int* __restrict__ rowp,
    const u16* __restrict__ W1T, const float* __restrict__ b1,  // W1T [128n][128k]
    const u16* __restrict__ W2T, const float* __restrict__ b2,  // W2T [64n][128k]
    const int* __restrict__ ebatch, float* __restrict__ gacc,
    int loff, int in_pool) {
  __shared__ u16 sh[2 * 64 * 136];       // xin | hid
  __shared__ float4 sacc[128];           // input-pool reduce (8 slots x 16 col-groups)
  u16* xin = sh;
  u16* hid = sh + 64 * 136;
  const int t = threadIdx.x;
  const int e0 = blockIdx.x * 64;
  const int lane = t & 63;
  const int wave = t >> 6;
  const int m16 = lane & 15;             // fragment row/col index
  const int quad = lane >> 4;            // k-subblock

  int g0 = ebatch[e0], g1 = ebatch[e0 + 63];
  const bool bnd = (g0 != g1);           // boundary (multi-graph) block, <=15 total

  // ---- preload B fragments (registers, straight from global; L2-hot) ----
  bf16x8 B1[2][4], B2[4];
#pragma unroll
  for (int ni = 0; ni < 2; ni++)
#pragma unroll
    for (int ki = 0; ki < 4; ki++)
      B1[ni][ki] = *(const bf16x8*)(W1T + (wave * 32 + ni * 16 + m16) * 128 + ki * 32 + quad * 8);
#pragma unroll
  for (int ki = 0; ki < 4; ki++)
    B2[ki] = *(const bf16x8*)(W2T + (wave * 16 + m16) * 128 + ki * 32 + quad * 8);

  // ---- stage xin[64][128] = [h[row[e]], ea[e]] as bf16 (+input pool, l=0) ----
  // Per-thread: c = (t&31)*4 is invariant; rows r = it*8 + (t>>5).
  const int c = (t & 31) * 4;
  const int rw = t >> 5;
  float4 vreg[8];
  if (c < 64) {                          // h-half: gather hbuf rows
#pragma unroll
    for (int it = 0; it < 8; it++) {
      int nd = rowp[e0 + it * 8 + rw];
      vreg[it] = *(const float4*)(hbuf + (size_t)nd * 64 + c);
    }
  } else {                               // ea-half: own rows
#pragma unroll
    for (int it = 0; it < 8; it++)
      vreg[it] = *(const float4*)(ea + (size_t)(e0 + it * 8 + rw) * 64 + (c - 64));
  }
  float ainx = 0.f, ainy = 0.f, ainz = 0.f, ainw = 0.f;
#pragma unroll
  for (int it = 0; it < 8; it++) {
    int r = it * 8 + rw;
    float4 v = vreg[it];
    if (in_pool && c >= 64) {
      if (!bnd) {
        ainx += v.x; ainy += v.y; ainz += v.z; ainw += v.w;
      } else {
        float* d = gacc + ebatch[e0 + r] * 256 + (c - 64);
        atomicAdd(d + 0, v.x); atomicAdd(d + 1, v.y);
        atomicAdd(d + 2, v.z); atomicAdd(d + 3, v.w);
      }
    }
    u32 p0 = (u32)f2bf(v.x) | ((u32)f2bf(v.y) << 16);
    u32 p1 = (u32)f2bf(v.z) | ((u32)f2bf(v.w) << 16);
    u32* dst = (u32*)&xin[r * 136 + c];
    dst[0] = p0;
    dst[1] = p1;
  }
  __syncthreads();

  // ---- GEMM1: [64x128] @ W1[128x128] -> hid, +bias, ReLU ----
  f32x4 zero = {0.f, 0.f, 0.f, 0.f};
  f32x4 acc1[2][4];
#pragma unroll
  for (int ni = 0; ni < 2; ni++)
#pragma unroll
    for (int mi = 0; mi < 4; mi++) acc1[ni][mi] = zero;

#pragma unroll
  for (int ki = 0; ki < 4; ki++) {
#pragma unroll
    for (int mi = 0; mi < 4; mi++) {
      bf16x8 A = *(const bf16x8*)&xin[(mi * 16 + m16) * 136 + ki * 32 + quad * 8];
      acc1[0][mi] = __builtin_amdgcn_mfma_f32_16x16x32_bf16(A, B1[0][ki], acc1[0][mi], 0, 0, 0);
      acc1[1][mi] = __builtin_amdgcn_mfma_f32_16x16x32_bf16(A, B1[1][ki], acc1[1][mi], 0, 0, 0);
    }
  }
  float b1v0 = b1[wave * 32 + m16];
  float b1v1 = b1[wave * 32 + 16 + m16];
#pragma unroll
  for (int mi = 0; mi < 4; mi++) {
#pragma unroll
    for (int reg = 0; reg < 4; reg++) {
      int r = mi * 16 + quad * 4 + reg;
      hid[r * 136 + wave * 32 + m16]      = f2bf(fmaxf(acc1[0][mi][reg] + b1v0, 0.f));
      hid[r * 136 + wave * 32 + 16 + m16] = f2bf(fmaxf(acc1[1][mi][reg] + b1v1, 0.f));
    }
  }
  __syncthreads();

  // ---- GEMM2: hid[64x128] @ W2[128x64] -> ea rows (in-place), +bias ----
  f32x4 acc2[4];
#pragma unroll
  for (int mi = 0; mi < 4; mi++) acc2[mi] = zero;
#pragma unroll
  for (int ki = 0; ki < 4; ki++) {
#pragma unroll
    for (int mi = 0; mi < 4; mi++) {
      bf16x8 A = *(const bf16x8*)&hid[(mi * 16 + m16) * 136 + ki * 32 + quad * 8];
      acc2[mi] = __builtin_amdgcn_mfma_f32_16x16x32_bf16(A, B2[ki], acc2[mi], 0, 0, 0);
    }
  }
  float b2v = b2[wave * 16 + m16];
#pragma unroll
  for (int mi = 0; mi < 4; mi++) {
#pragma unroll
    for (int reg = 0; reg < 4; reg++) {
      int r = mi * 16 + quad * 4 + reg;
      ea[(size_t)(e0 + r) * 64 + wave * 16 + m16] = acc2[mi][reg] + b2v;
    }
  }

  // ---- fused ge pooling of OUTPUT rows ----
  int colo = wave * 16 + m16;
  if (!bnd) {                            // fast path: single-graph block
    float s = 0.f;
#pragma unroll
    for (int mi = 0; mi < 4; mi++)
#pragma unroll
      for (int reg = 0; reg < 4; reg++) s += acc2[mi][reg] + b2v;
    s += __shfl_xor(s, 16);
    s += __shfl_xor(s, 32);
    if (quad == 0) atomicAdd(&gacc[g0 * 256 + loff + colo], s);
  } else {                               // boundary block: per-value atomics
#pragma unroll
    for (int mi = 0; mi < 4; mi++)
#pragma unroll
      for (int reg = 0; reg < 4; reg++) {
        int r = mi * 16 + quad * 4 + reg;
        atomicAdd(&gacc[ebatch[e0 + r] * 256 + loff + colo], acc2[mi][reg] + b2v);
      }
  }

  // ---- input-pool reduce (layer 0, single-graph blocks) ----
  if (in_pool) {
    if (!bnd && (t & 31) >= 16) {
      float4 a = {ainx, ainy, ainz, ainw};
      sacc[(t >> 5) * 16 + (t & 31) - 16] = a;
    }
    __syncthreads();
    if (!bnd && t < 16) {
      float Sx = 0.f, Sy = 0.f, Sz = 0.f, Sw = 0.f;
#pragma unroll
      for (int sl = 0; sl < 8; sl++) {
        float4 v = sacc[sl * 16 + t];
        Sx += v.x; Sy += v.y; Sz += v.z; Sw += v.w;
      }
      float* d = gacc + g0 * 256 + t * 4;
      atomicAdd(d + 0, Sx); atomicAdd(d + 1, Sy);
      atomicAdd(d + 2, Sz); atomicAdd(d + 3, Sw);
    }
  }
}

// ---------- finalize: means (acc already in output layout), head, f32 out ----------
__global__ __launch_bounds__(256) void finalize_k(
    const float* gn_acc, const float* ge_acc,
    const int* cnt_n, const int* cnt_e,
    const float* Wo1, const float* bo1,
    const float* Wo2, const float* bo2,
    const float* Wo3, const float* bo3,
    float* out) {
  __shared__ float attr[16][512];
  __shared__ float o1[16][128];
  __shared__ float o2[16][128];
  int t = threadIdx.x;
  for (int i = t; i < 4096; i += 256) {
    int g = i >> 8, c = i & 255;
    float vn = gn_acc[i] / (float)max(cnt_n[g], 1);
    float ve = ge_acc[i] / (float)max(cnt_e[g], 1);
    out[i] = vn;
    out[4096 + i] = ve;
    attr[g][c] = vn;
    attr[g][256 + c] = ve;
  }
  __syncthreads();
  {
    int j = t & 127, gh = t >> 7;
    float a[8];
#pragma unroll
    for (int q = 0; q < 8; q++) a[q] = bo1[j];
    for (int k = 0; k < 512; k++) {
      float w = Wo1[k * 128 + j];
#pragma unroll
      for (int q = 0; q < 8; q++) a[q] = fmaf(attr[gh * 8 + q][k], w, a[q]);
    }
#pragma unroll
    for (int q = 0; q < 8; q++) o1[gh * 8 + q][j] = fmaxf(a[q], 0.f);
  }
  __syncthreads();
  {
    int j = t & 127, gh = t >> 7;
    float a[8];
#pragma unroll
    for (int q = 0; q < 8; q++) a[q] = bo2[j];
    for (int k = 0; k < 128; k++) {
      float w = Wo2[k * 128 + j];
#pragma unroll
      for (int q = 0; q < 8; q++) a[q] = fmaf(o1[gh * 8 + q][k], w, a[q]);
    }
#pragma unroll
    for (int q = 0; q < 8; q++) o2[gh * 8 + q][j] = fmaxf(a[q], 0.f);
  }
  __syncthreads();
  {
    int j = t & 31, gb = t >> 5;
#pragma unroll
    for (int q = 0; q < 2; q++) {
      int g = gb * 2 + q;
      float a = bo3[j];
      for (int k = 0; k < 128; k++) a = fmaf(o2[g][k], Wo3[k * 32 + j], a);
      out[8192 + g * 32 + j] = a;
    }
  }
}

extern "C" void kernel_launch(void* const* d_in, const int* in_sizes, int n_in,
                              void* d_out, int out_size, void* d_ws, size_t ws_size,
                              hipStream_t stream) {
  float* ea = (float*)d_in[1];               // [NE,64] f32, updated IN-PLACE
  const int* edge_index = (const int*)d_in[3];
  const int* row = edge_index;
  const int* col = edge_index + NE;
  const int* batch = (const int*)d_in[4];
  const int* ebatch = (const int*)d_in[5];
  const float* W1s = (const float*)d_in[6];  // [3,128,128]
  const float* b1s = (const float*)d_in[7];  // [3,128]
  const float* W2s = (const float*)d_in[8];  // [3,128,64]
  const float* b2s = (const float*)d_in[9];  // [3,64]
  const float* Wo1 = (const float*)d_in[10];
  const float* bo1 = (const float*)d_in[11];
  const float* Wo2 = (const float*)d_in[12];
  const float* bo2 = (const float*)d_in[13];
  const float* Wo3 = (const float*)d_in[14];
  const float* bo3 = (const float*)d_in[15];

  char* p = (char*)d_ws;
  auto alloc = [&](size_t b) { char* r = p; p += (b + 255) & ~(size_t)255; return r; };
  // ---- zero region (one memset) ----
  int* deg = (int*)alloc(NN * 4);
  int* cursor = (int*)alloc(NN * 4);
  int* cnt_n = (int*)alloc(64);
  int* cnt_e = (int*)alloc(64);
  float* gn_acc = (float*)alloc(NGR * 256 * 4);
  float* ge_acc = (float*)alloc(NGR * 256 * 4);
  size_t zbytes = (size_t)(p - (char*)d_ws);
  // ---- non-zeroed ----
  int* csr_off = (int*)alloc((NN + 1) * 4);
  int* csr_eid = (int*)alloc((size_t)NE * 4);
  float* hbuf = (float*)alloc((size_t)NN * 64 * 4);
  u16* W1T = (u16*)alloc(3 * 128 * 128 * 2);
  u16* W2T = (u16*)alloc(3 * 64 * 128 * 2);

  hipMemsetAsync(d_ws, 0, zbytes, stream);

  prep_w_k<<<(3 * 128 * 128 + 3 * 128 * 64 + 255) / 256, 256, 0, stream>>>(W1s, W2s, W1T, W2T);
  hist_deg<<<(NE + 255) / 256, 256, 0, stream>>>(col, deg);
  count_graphs<<<1, 64, 0, stream>>>(batch, ebatch, cnt_n, cnt_e);
  scan_deg<<<1, 256, 0, stream>>>(deg, csr_off);
  fill_csr<<<(NE + 255) / 256, 256, 0, stream>>>(col, csr_off, cursor, csr_eid);

  // layer-0 gn pool on raw edge_attr (ge layer-0 pool fused into mlp l=0)
  gather_k<<<2048, 256, 0, stream>>>(ea, csr_off, csr_eid, batch, hbuf, gn_acc, 0, 1);

  for (int l = 0; l < 3; l++) {
    mlp_mfma_k<<<NE / 64, 256, 0, stream>>>(hbuf, ea, row,
        W1T + l * 16384, b1s + l * 128, W2T + l * 8192, b2s + l * 64,
        ebatch, ge_acc, (l + 1) * 64, l == 0 ? 1 : 0);
    gather_k<<<2048, 256, 0, stream>>>(ea, csr_off, csr_eid, batch, hbuf,
                                       gn_acc, (l + 1) * 64, l < 2 ? 1 : 0);
  }

  finalize_k<<<1, 256, 0, stream>>>(gn_acc, ge_acc, cnt_n, cnt_e,
      Wo1, bo1, Wo2, bo2, Wo3, bo3, (float*)d_out);
}

// Round 6
// 2657.490 us; speedup vs baseline: 1.0131x; 1.0131x over previous
//
#include <hip/hip_runtime.h>

#define NN 50000      // nodes
#define NE 800000     // edges
#define NGR 16        // graphs

typedef unsigned short u16;
typedef unsigned int u32;
typedef __attribute__((ext_vector_type(8))) short bf16x8;
typedef __attribute__((ext_vector_type(4))) float f32x4;

__device__ __forceinline__ u16 f2bf(float f) {       // RNE f32->bf16
  u32 u = __float_as_uint(f);
  return (u16)((u + 0x7fffu + ((u >> 16) & 1u)) >> 16);
}

// ---------- degree histogram ----------
__global__ void hist_deg(const int* col, int* deg) {
  int e = blockIdx.x * blockDim.x + threadIdx.x;
  if (e < NE) atomicAdd(&deg[col[e]], 1);
}

// ---------- per-graph counts (sorted ids) + edge segment offsets ----------
__device__ int lbound(const int* a, int n, int v) {
  int lo = 0, hi = n;
  while (lo < hi) { int m = (lo + hi) >> 1; if (a[m] < v) lo = m + 1; else hi = m; }
  return lo;
}
__global__ void count_graphs(const int* batch, const int* ebatch, int* cnt_n, int* cnt_e,
                             int* eoff) {
  int t = threadIdx.x;
  if (t < NGR) cnt_n[t] = lbound(batch, NN, t + 1) - lbound(batch, NN, t);
  else if (t < 2 * NGR) { int g = t - NGR; cnt_e[g] = lbound(ebatch, NE, g + 1) - lbound(ebatch, NE, g); }
  else if (t < 3 * NGR + 1) { int g = t - 2 * NGR; eoff[g] = lbound(ebatch, NE, g); }  // eoff[16]=NE
}

// ---------- exclusive scan of deg -> csr_off (single block) ----------
__global__ __launch_bounds__(256) void scan_deg(const int* deg, int* off) {
  __shared__ int sums[256];
  const int CH = (NN + 255) / 256;
  int t = threadIdx.x;
  int base = t * CH;
  int s = 0;
  for (int i = 0; i < CH; i++) { int idx = base + i; if (idx < NN) s += deg[idx]; }
  sums[t] = s;
  __syncthreads();
  for (int d = 1; d < 256; d <<= 1) {
    int v = (t >= d) ? sums[t - d] : 0;
    __syncthreads();
    sums[t] += v;
    __syncthreads();
  }
  int run = (t == 0) ? 0 : sums[t - 1];
  for (int i = 0; i < CH; i++) { int idx = base + i; if (idx < NN) { off[idx] = run; run += deg[idx]; } }
  if (t == 255) off[NN] = run;
}

// ---------- CSR fill ----------
__global__ void fill_csr(const int* col, const int* off, int* cursor, int* eid) {
  int e = blockIdx.x * blockDim.x + threadIdx.x;
  if (e < NE) {
    int c = col[e];
    int p = atomicAdd(&cursor[c], 1);
    eid[off[c] + p] = e;
  }
}

// ---------- weights f32 -> bf16 TRANSPOSED (W1T[l][n][k], W2T[l][n][k]) ----------
__global__ void prep_w_k(const float* W1, const float* W2, u16* W1T, u16* W2T) {
  int i = blockIdx.x * 256 + threadIdx.x;
  if (i < 3 * 128 * 128) {
    int l = i / 16384, k = (i >> 7) & 127, n = i & 127;
    W1T[l * 16384 + n * 128 + k] = f2bf(W1[i]);
  } else {
    int j = i - 3 * 128 * 128;
    if (j < 3 * 128 * 64) {
      int l = j / 8192, k = (j >> 6) & 127, n = j & 63;
      W2T[l * 8192 + n * 128 + k] = f2bf(W2[j]);
    }
  }
}

// ---------- layer-0 ge pool, SEGMENTED: per-wave chunk split at graph ----------
// boundaries ONCE (via eoff), then a pure load/accumulate inner loop — no
// per-row ebatch load/compare/flush. Full-wave 256B rows, 8 loads in flight.
__global__ __launch_bounds__(256) void pool_seg_k(const float* __restrict__ ea,
                                                  const int* __restrict__ eoff,
                                                  float* __restrict__ gacc, int loff) {
  int gid = blockIdx.x * blockDim.x + threadIdx.x;
  int w = gid >> 6, lane = gid & 63;
  const int NW = (gridDim.x * blockDim.x) >> 6;
  const int CH = (NE + NW - 1) / NW;
  int r0 = w * CH, r1 = min(r0 + CH, NE);
  if (r0 >= r1) return;
  int g = 0;
  while (eoff[g + 1] <= r0) g++;       // <=16 scalar iters, once per wave
  const float* base = ea + lane;
  while (r0 < r1) {
    int gend = min(r1, eoff[g + 1]);
    float a0 = 0.f, a1 = 0.f, a2 = 0.f, a3 = 0.f;
    float a4 = 0.f, a5 = 0.f, a6 = 0.f, a7 = 0.f;
    int r = r0;
    for (; r + 8 <= gend; r += 8) {    // 8 independent 256B row loads in flight
      float v0 = base[(size_t)(r + 0) * 64];
      float v1 = base[(size_t)(r + 1) * 64];
      float v2 = base[(size_t)(r + 2) * 64];
      float v3 = base[(size_t)(r + 3) * 64];
      float v4 = base[(size_t)(r + 4) * 64];
      float v5 = base[(size_t)(r + 5) * 64];
      float v6 = base[(size_t)(r + 6) * 64];
      float v7 = base[(size_t)(r + 7) * 64];
      a0 += v0; a1 += v1; a2 += v2; a3 += v3;
      a4 += v4; a5 += v5; a6 += v6; a7 += v7;
    }
    for (; r < gend; r++) a0 += base[(size_t)r * 64];
    float s = ((a0 + a1) + (a2 + a3)) + ((a4 + a5) + (a6 + a7));
    atomicAdd(&gacc[g * 256 + loff + lane], s);   // one flush per segment
    r0 = gend;
    g++;
  }
}

// ---------- h = CSR gather-mean of ea; pool h by batch -> gacc[g*256+loff+d] ----------
// Half-wave split: 32 lanes x float2 per row -> each load instr covers 2 edge
// rows; 4 explicit loads per iter = 8 rows in flight per wave.
__global__ __launch_bounds__(256) void gather_k(
    const float* __restrict__ ea, const int* __restrict__ off,
    const int* __restrict__ eid, const int* __restrict__ batch,
    float* __restrict__ hbuf, float* __restrict__ gacc,
    int loff, int store_h) {
  int gid = blockIdx.x * blockDim.x + threadIdx.x;
  int w = gid >> 6, lane = gid & 63;
  int nw = (gridDim.x * blockDim.x) >> 6;
  int h = lane >> 5, l = lane & 31;
  const float* base = ea + l * 2;      // float2 column base for this lane
  for (int n = w; n < NN; n += nw) {
    int s = off[n], e = off[n + 1];
    int g = batch[n];
    float a0x = 0.f, a0y = 0.f, a1x = 0.f, a1y = 0.f;
    float a2x = 0.f, a2y = 0.f, a3x = 0.f, a3y = 0.f;
    int i = s;
    for (; i + 8 <= e; i += 8) {       // 8 edges per iter, this half takes 4
      int e0 = eid[i + h];
      int e1 = eid[i + 2 + h];
      int e2 = eid[i + 4 + h];
      int e3 = eid[i + 6 + h];
      float2 v0 = *(const float2*)(base + (size_t)e0 * 64);
      float2 v1 = *(const float2*)(base + (size_t)e1 * 64);
      float2 v2 = *(const float2*)(base + (size_t)e2 * 64);
      float2 v3 = *(const float2*)(base + (size_t)e3 * 64);
      a0x += v0.x; a0y += v0.y;
      a1x += v1.x; a1y += v1.y;
      a2x += v2.x; a2y += v2.y;
      a3x += v3.x; a3y += v3.y;
    }
    for (; i + 2 <= e; i += 2) {       // pair tail
      int e0 = eid[i + h];
      float2 v = *(const float2*)(base + (size_t)e0 * 64);
      a0x += v.x; a0y += v.y;
    }
    if (i < e && h == 0) {             // single leftover edge
      int e0 = eid[i];
      float2 v = *(const float2*)(base + (size_t)e0 * 64);
      a0x += v.x; a0y += v.y;
    }
    float sx = (a0x + a1x) + (a2x + a3x);
    float sy = (a0y + a1y) + (a2y + a3y);
    sx += __shfl_xor(sx, 32);
    sy += __shfl_xor(sy, 32);
    if (h == 0) {
      float inv = 1.f / (float)max(e - s, 1);
      float hx = sx * inv, hy = sy * inv;
      if (store_h) {
        float2 hv = {hx, hy};
        *(float2*)(hbuf + (size_t)n * 64 + l * 2) = hv;
      }
      float* dst = gacc + g * 256 + loff + l * 2;
      atomicAdd(dst + 0, hx);
      atomicAdd(dst + 1, hy);
    }
  }
}

// ---------- edge MLP via bf16 MFMA: ea = relu([h[row],ea]@W1+b1)@W2+b2, in-place ----------
// Block = 256 thr (4 waves), 64 edges. Fused ge-pool epilogue (ebatch sorted ->
// block is single-graph except <=15 boundary blocks).  [byte-exact round-2 version]
__global__ __launch_bounds__(256) void mlp_mfma_k(
    const float* hbuf, float* ea, const int* rowp,
    const u16* W1T, const float* b1,     // W1T [128n][128k] bf16
    const u16* W2T, const float* b2,     // W2T [64n][128k] bf16
    const int* ebatch, float* gacc, int loff) {
  __shared__ u16 sh[2 * 64 * 136];       // xin | hid
  u16* xin = sh;
  u16* hid = sh + 64 * 136;
  const int t = threadIdx.x;
  const int e0 = blockIdx.x * 64;
  const int lane = t & 63;
  const int wave = t >> 6;
  const int m16 = lane & 15;             // fragment row/col index
  const int quad = lane >> 4;            // k-subblock

  // ---- preload B fragments (registers, straight from global; L2-hot) ----
  bf16x8 B1[2][4], B2[4];
#pragma unroll
  for (int ni = 0; ni < 2; ni++)
#pragma unroll
    for (int ki = 0; ki < 4; ki++)
      B1[ni][ki] = *(const bf16x8*)(W1T + (wave * 32 + ni * 16 + m16) * 128 + ki * 32 + quad * 8);
#pragma unroll
  for (int ki = 0; ki < 4; ki++)
    B2[ki] = *(const bf16x8*)(W2T + (wave * 16 + m16) * 128 + ki * 32 + quad * 8);

  // ---- stage xin[64][128] = [h[row[e]], ea[e]] as bf16 ----
#pragma unroll
  for (int it = 0; it < 8; it++) {
    int f = it * 256 + t;                // float4 id 0..2047
    int r = f >> 5;                      // edge row 0..63
    int c = (f & 31) * 4;                // col 0..124
    const float* src;
    if (c < 64) {
      int nd = rowp[e0 + r];
      src = hbuf + (size_t)nd * 64 + c;
    } else {
      src = ea + (size_t)(e0 + r) * 64 + (c - 64);
    }
    float4 v = *(const float4*)src;
    u32 p0 = (u32)f2bf(v.x) | ((u32)f2bf(v.y) << 16);
    u32 p1 = (u32)f2bf(v.z) | ((u32)f2bf(v.w) << 16);
    u32* dst = (u32*)&xin[r * 136 + c];
    dst[0] = p0;
    dst[1] = p1;
  }
  __syncthreads();

  // ---- GEMM1: [64x128] @ W1[128x128] -> hid, +bias, ReLU ----
  f32x4 zero = {0.f, 0.f, 0.f, 0.f};
  f32x4 acc1[2][4];
#pragma unroll
  for (int ni = 0; ni < 2; ni++)
#pragma unroll
    for (int mi = 0; mi < 4; mi++) acc1[ni][mi] = zero;

#pragma unroll
  for (int ki = 0; ki < 4; ki++) {
#pragma unroll
    for (int mi = 0; mi < 4; mi++) {
      bf16x8 A = *(const bf16x8*)&xin[(mi * 16 + m16) * 136 + ki * 32 + quad * 8];
      acc1[0][mi] = __builtin_amdgcn_mfma_f32_16x16x32_bf16(A, B1[0][ki], acc1[0][mi], 0, 0, 0);
      acc1[1][mi] = __builtin_amdgcn_mfma_f32_16x16x32_bf16(A, B1[1][ki], acc1[1][mi], 0, 0, 0);
    }
  }
  float b1v0 = b1[wave * 32 + m16];
  float b1v1 = b1[wave * 32 + 16 + m16];
#pragma unroll
  for (int mi = 0; mi < 4; mi++) {
#pragma unroll
    for (int reg = 0; reg < 4; reg++) {
      int r = mi * 16 + quad * 4 + reg;
      hid[r * 136 + wave * 32 + m16]      = f2bf(fmaxf(acc1[0][mi][reg] + b1v0, 0.f));
      hid[r * 136 + wave * 32 + 16 + m16] = f2bf(fmaxf(acc1[1][mi][reg] + b1v1, 0.f));
    }
  }
  __syncthreads();

  // ---- GEMM2: hid[64x128] @ W2[128x64] -> ea rows (in-place), +bias ----
  f32x4 acc2[4];
#pragma unroll
  for (int mi = 0; mi < 4; mi++) acc2[mi] = zero;
#pragma unroll
  for (int ki = 0; ki < 4; ki++) {
#pragma unroll
    for (int mi = 0; mi < 4; mi++) {
      bf16x8 A = *(const bf16x8*)&hid[(mi * 16 + m16) * 136 + ki * 32 + quad * 8];
      acc2[mi] = __builtin_amdgcn_mfma_f32_16x16x32_bf16(A, B2[ki], acc2[mi], 0, 0, 0);
    }
  }
  float b2v = b2[wave * 16 + m16];
#pragma unroll
  for (int mi = 0; mi < 4; mi++) {
#pragma unroll
    for (int reg = 0; reg < 4; reg++) {
      int r = mi * 16 + quad * 4 + reg;
      ea[(size_t)(e0 + r) * 64 + wave * 16 + m16] = acc2[mi][reg] + b2v;
    }
  }

  // ---- fused ge pooling: sum this block's 64 output rows per graph ----
  int g0 = ebatch[e0], g1 = ebatch[e0 + 63];
  int colo = wave * 16 + m16;
  if (g0 == g1) {                        // fast path: single-graph block
    float s = 0.f;
#pragma unroll
    for (int mi = 0; mi < 4; mi++)
#pragma unroll
      for (int reg = 0; reg < 4; reg++) s += acc2[mi][reg] + b2v;
    s += __shfl_xor(s, 16);
    s += __shfl_xor(s, 32);
    if (quad == 0) atomicAdd(&gacc[g0 * 256 + loff + colo], s);
  } else {                               // boundary block (<=15 total): per-value atomics
#pragma unroll
    for (int mi = 0; mi < 4; mi++)
#pragma unroll
      for (int reg = 0; reg < 4; reg++) {
        int r = mi * 16 + quad * 4 + reg;
        atomicAdd(&gacc[ebatch[e0 + r] * 256 + loff + colo], acc2[mi][reg] + b2v);
      }
  }
}

// ---------- finalize: means (acc already in output layout), head, f32 out ----------
__global__ __launch_bounds__(256) void finalize_k(
    const float* gn_acc, const float* ge_acc,
    const int* cnt_n, const int* cnt_e,
    const float* Wo1, const float* bo1,
    const float* Wo2, const float* bo2,
    const float* Wo3, const float* bo3,
    float* out) {
  __shared__ float attr[16][512];
  __shared__ float o1[16][128];
  __shared__ float o2[16][128];
  int t = threadIdx.x;
  for (int i = t; i < 4096; i += 256) {
    int g = i >> 8, c = i & 255;
    float vn = gn_acc[i] / (float)max(cnt_n[g], 1);
    float ve = ge_acc[i] / (float)max(cnt_e[g], 1);
    out[i] = vn;
    out[4096 + i] = ve;
    attr[g][c] = vn;
    attr[g][256 + c] = ve;
  }
  __syncthreads();
  {
    int j = t & 127, gh = t >> 7;
    float a[8];
#pragma unroll
    for (int q = 0; q < 8; q++) a[q] = bo1[j];
    for (int k = 0; k < 512; k++) {
      float w = Wo1[k * 128 + j];
#pragma unroll
      for (int q = 0; q < 8; q++) a[q] = fmaf(attr[gh * 8 + q][k], w, a[q]);
    }
#pragma unroll
    for (int q = 0; q < 8; q++) o1[gh * 8 + q][j] = fmaxf(a[q], 0.f);
  }
  __syncthreads();
  {
    int j = t & 127, gh = t >> 7;
    float a[8];
#pragma unroll
    for (int q = 0; q < 8; q++) a[q] = bo2[j];
    for (int k = 0; k < 128; k++) {
      float w = Wo2[k * 128 + j];
#pragma unroll
      for (int q = 0; q < 8; q++) a[q] = fmaf(o1[gh * 8 + q][k], w, a[q]);
    }
#pragma unroll
    for (int q = 0; q < 8; q++) o2[gh * 8 + q][j] = fmaxf(a[q], 0.f);
  }
  __syncthreads();
  {
    int j = t & 31, gb = t >> 5;
#pragma unroll
    for (int q = 0; q < 2; q++) {
      int g = gb * 2 + q;
      float a = bo3[j];
      for (int k = 0; k < 128; k++) a = fmaf(o2[g][k], Wo3[k * 32 + j], a);
      out[8192 + g * 32 + j] = a;
    }
  }
}

extern "C" void kernel_launch(void* const* d_in, const int* in_sizes, int n_in,
                              void* d_out, int out_size, void* d_ws, size_t ws_size,
                              hipStream_t stream) {
  float* ea = (float*)d_in[1];               // [NE,64] f32, updated IN-PLACE
  const int* edge_index = (const int*)d_in[3];
  const int* row = edge_index;
  const int* col = edge_index + NE;
  const int* batch = (const int*)d_in[4];
  const int* ebatch = (const int*)d_in[5];
  const float* W1s = (const float*)d_in[6];  // [3,128,128]
  const float* b1s = (const float*)d_in[7];  // [3,128]
  const float* W2s = (const float*)d_in[8];  // [3,128,64]
  const float* b2s = (const float*)d_in[9];  // [3,64]
  const float* Wo1 = (const float*)d_in[10];
  const float* bo1 = (const float*)d_in[11];
  const float* Wo2 = (const float*)d_in[12];
  const float* bo2 = (const float*)d_in[13];
  const float* Wo3 = (const float*)d_in[14];
  const float* bo3 = (const float*)d_in[15];

  char* p = (char*)d_ws;
  auto alloc = [&](size_t b) { char* r = p; p += (b + 255) & ~(size_t)255; return r; };
  // ---- zero region (one memset) ----
  int* deg = (int*)alloc(NN * 4);
  int* cursor = (int*)alloc(NN * 4);
  int* cnt_n = (int*)alloc(64);
  int* cnt_e = (int*)alloc(64);
  float* gn_acc = (float*)alloc(NGR * 256 * 4);
  float* ge_acc = (float*)alloc(NGR * 256 * 4);
  size_t zbytes = (size_t)(p - (char*)d_ws);
  // ---- non-zeroed ----
  int* csr_off = (int*)alloc((NN + 1) * 4);
  int* csr_eid = (int*)alloc((size_t)NE * 4);
  float* hbuf = (float*)alloc((size_t)NN * 64 * 4);
  u16* W1T = (u16*)alloc(3 * 128 * 128 * 2);
  u16* W2T = (u16*)alloc(3 * 64 * 128 * 2);
  int* eoff = (int*)alloc((NGR + 1) * 4);

  hipMemsetAsync(d_ws, 0, zbytes, stream);

  prep_w_k<<<(3 * 128 * 128 + 3 * 128 * 64 + 255) / 256, 256, 0, stream>>>(W1s, W2s, W1T, W2T);
  hist_deg<<<(NE + 255) / 256, 256, 0, stream>>>(col, deg);
  count_graphs<<<1, 64, 0, stream>>>(batch, ebatch, cnt_n, cnt_e, eoff);
  scan_deg<<<1, 256, 0, stream>>>(deg, csr_off);
  fill_csr<<<(NE + 255) / 256, 256, 0, stream>>>(col, csr_off, cursor, csr_eid);

  // layer-0 pools on raw edge_attr
  pool_seg_k<<<2048, 256, 0, stream>>>(ea, eoff, ge_acc, 0);
  gather_k<<<2048, 256, 0, stream>>>(ea, csr_off, csr_eid, batch, hbuf, gn_acc, 0, 1);

  for (int l = 0; l < 3; l++) {
    mlp_mfma_k<<<NE / 64, 256, 0, stream>>>(hbuf, ea, row,
        W1T + l * 16384, b1s + l * 128, W2T + l * 8192, b2s + l * 64,
        ebatch, ge_acc, (l + 1) * 64);
    gather_k<<<2048, 256, 0, stream>>>(ea, csr_off, csr_eid, batch, hbuf,
                                       gn_acc, (l + 1) * 64, l < 2 ? 1 : 0);
  }

  finalize_k<<<1, 256, 0, stream>>>(gn_acc, ge_acc, cnt_n, cnt_e,
      Wo1, bo1, Wo2, bo2, Wo3, bo3, (float*)d_out);
}

// Round 7
// 2158.130 us; speedup vs baseline: 1.2475x; 1.2314x over previous
//
#include <hip/hip_runtime.h>

#define NN 50000      // nodes
#define NE 800000     // edges
#define NGR 16        // graphs

typedef unsigned short u16;
typedef unsigned int u32;
typedef __attribute__((ext_vector_type(8))) short bf16x8;
typedef __attribute__((ext_vector_type(4))) float f32x4;

__device__ __forceinline__ u16 f2bf(float f) {       // RNE f32->bf16
  u32 u = __float_as_uint(f);
  return (u16)((u + 0x7fffu + ((u >> 16) & 1u)) >> 16);
}

// ---------- degree histogram ----------
__global__ void hist_deg(const int* col, int* deg) {
  int e = blockIdx.x * blockDim.x + threadIdx.x;
  if (e < NE) atomicAdd(&deg[col[e]], 1);
}

// ---------- per-graph counts (sorted ids) + edge segment offsets ----------
__device__ int lbound(const int* a, int n, int v) {
  int lo = 0, hi = n;
  while (lo < hi) { int m = (lo + hi) >> 1; if (a[m] < v) lo = m + 1; else hi = m; }
  return lo;
}
__global__ void count_graphs(const int* batch, const int* ebatch, int* cnt_n, int* cnt_e,
                             int* eoff) {
  int t = threadIdx.x;
  if (t < NGR) cnt_n[t] = lbound(batch, NN, t + 1) - lbound(batch, NN, t);
  else if (t < 2 * NGR) { int g = t - NGR; cnt_e[g] = lbound(ebatch, NE, g + 1) - lbound(ebatch, NE, g); }
  else if (t < 3 * NGR + 1) { int g = t - 2 * NGR; eoff[g] = lbound(ebatch, NE, g); }  // eoff[16]=NE
}

// ---------- exclusive scan of deg -> csr_off (single block) ----------
__global__ __launch_bounds__(256) void scan_deg(const int* deg, int* off) {
  __shared__ int sums[256];
  const int CH = (NN + 255) / 256;
  int t = threadIdx.x;
  int base = t * CH;
  int s = 0;
  for (int i = 0; i < CH; i++) { int idx = base + i; if (idx < NN) s += deg[idx]; }
  sums[t] = s;
  __syncthreads();
  for (int d = 1; d < 256; d <<= 1) {
    int v = (t >= d) ? sums[t - d] : 0;
    __syncthreads();
    sums[t] += v;
    __syncthreads();
  }
  int run = (t == 0) ? 0 : sums[t - 1];
  for (int i = 0; i < CH; i++) { int idx = base + i; if (idx < NN) { off[idx] = run; run += deg[idx]; } }
  if (t == 255) off[NN] = run;
}

// ---------- CSR fill: eid (fallback path) + pos (permutation) ----------
__global__ void fill_csr(const int* col, const int* off, int* cursor, int* eid, int* pos) {
  int e = blockIdx.x * blockDim.x + threadIdx.x;
  if (e < NE) {
    int c = col[e];
    int p = atomicAdd(&cursor[c], 1);
    int slot = off[c] + p;
    eid[slot] = e;
    pos[e] = slot;
  }
}

// ---------- weights f32 -> bf16 TRANSPOSED (W1T[l][n][k], W2T[l][n][k]) ----------
__global__ void prep_w_k(const float* W1, const float* W2, u16* W1T, u16* W2T) {
  int i = blockIdx.x * 256 + threadIdx.x;
  if (i < 3 * 128 * 128) {
    int l = i / 16384, k = (i >> 7) & 127, n = i & 127;
    W1T[l * 16384 + n * 128 + k] = f2bf(W1[i]);
  } else {
    int j = i - 3 * 128 * 128;
    if (j < 3 * 128 * 64) {
      int l = j / 8192, k = (j >> 6) & 127, n = j & 63;
      W2T[l * 8192 + n * 128 + k] = f2bf(W2[j]);
    }
  }
}

// ---------- layer-0: segmented ge pool + CSR permute (esrt[pos[e]] = ea[e]) ----------
// Streaming reads, scatter writes (writes don't stall), one atomic flush/segment.
__global__ __launch_bounds__(256) void pool_perm_k(const float* __restrict__ ea,
                                                   const int* __restrict__ eoff,
                                                   const int* __restrict__ pos,
                                                   float* __restrict__ esrt,
                                                   float* __restrict__ gacc, int loff) {
  int gid = blockIdx.x * blockDim.x + threadIdx.x;
  int w = gid >> 6, lane = gid & 63;
  const int NW = (gridDim.x * blockDim.x) >> 6;
  const int CH = (NE + NW - 1) / NW;
  int r0 = w * CH, r1 = min(r0 + CH, NE);
  if (r0 >= r1) return;
  int g = 0;
  while (eoff[g + 1] <= r0) g++;       // <=16 scalar iters, once per wave
  const float* base = ea + lane;
  float* sbase = esrt + lane;
  while (r0 < r1) {
    int gend = min(r1, eoff[g + 1]);
    float a0 = 0.f, a1 = 0.f, a2 = 0.f, a3 = 0.f;
    float a4 = 0.f, a5 = 0.f, a6 = 0.f, a7 = 0.f;
    int r = r0;
    for (; r + 8 <= gend; r += 8) {    // 8 independent 256B row loads in flight
      float v0 = base[(size_t)(r + 0) * 64];
      float v1 = base[(size_t)(r + 1) * 64];
      float v2 = base[(size_t)(r + 2) * 64];
      float v3 = base[(size_t)(r + 3) * 64];
      float v4 = base[(size_t)(r + 4) * 64];
      float v5 = base[(size_t)(r + 5) * 64];
      float v6 = base[(size_t)(r + 6) * 64];
      float v7 = base[(size_t)(r + 7) * 64];
      sbase[(size_t)pos[r + 0] * 64] = v0;
      sbase[(size_t)pos[r + 1] * 64] = v1;
      sbase[(size_t)pos[r + 2] * 64] = v2;
      sbase[(size_t)pos[r + 3] * 64] = v3;
      sbase[(size_t)pos[r + 4] * 64] = v4;
      sbase[(size_t)pos[r + 5] * 64] = v5;
      sbase[(size_t)pos[r + 6] * 64] = v6;
      sbase[(size_t)pos[r + 7] * 64] = v7;
      a0 += v0; a1 += v1; a2 += v2; a3 += v3;
      a4 += v4; a5 += v5; a6 += v6; a7 += v7;
    }
    for (; r < gend; r++) {
      float v = base[(size_t)r * 64];
      sbase[(size_t)pos[r] * 64] = v;
      a0 += v;
    }
    float s = ((a0 + a1) + (a2 + a3)) + ((a4 + a5) + (a6 + a7));
    atomicAdd(&gacc[g * 256 + loff + lane], s);   // one flush per segment
    r0 = gend;
    g++;
  }
}

// ---------- STREAMING gather: h[n] = mean of contiguous esrt rows [off[n],off[n+1]) ----------
__global__ __launch_bounds__(256) void gather_seq_k(
    const float* __restrict__ esrt, const int* __restrict__ off,
    const int* __restrict__ batch, float* __restrict__ hbuf,
    float* __restrict__ gacc, int loff, int store_h) {
  int gid = blockIdx.x * blockDim.x + threadIdx.x;
  int w = gid >> 6, lane = gid & 63;
  int nw = (gridDim.x * blockDim.x) >> 6;
  const float* base = esrt + lane;
  for (int n = w; n < NN; n += nw) {
    int s = off[n], e = off[n + 1];
    float a0 = 0.f, a1 = 0.f, a2 = 0.f, a3 = 0.f;
    float a4 = 0.f, a5 = 0.f, a6 = 0.f, a7 = 0.f;
    int i = s;
    for (; i + 8 <= e; i += 8) {
      a0 += base[(size_t)(i + 0) * 64];
      a1 += base[(size_t)(i + 1) * 64];
      a2 += base[(size_t)(i + 2) * 64];
      a3 += base[(size_t)(i + 3) * 64];
      a4 += base[(size_t)(i + 4) * 64];
      a5 += base[(size_t)(i + 5) * 64];
      a6 += base[(size_t)(i + 6) * 64];
      a7 += base[(size_t)(i + 7) * 64];
    }
    for (; i + 4 <= e; i += 4) {
      a0 += base[(size_t)(i + 0) * 64];
      a1 += base[(size_t)(i + 1) * 64];
      a2 += base[(size_t)(i + 2) * 64];
      a3 += base[(size_t)(i + 3) * 64];
    }
    for (; i < e; i++) a0 += base[(size_t)i * 64];
    float acc = ((a0 + a1) + (a2 + a3)) + ((a4 + a5) + (a6 + a7));
    float hv = acc / (float)max(e - s, 1);
    if (store_h) hbuf[(size_t)n * 64 + lane] = hv;
    atomicAdd(&gacc[batch[n] * 256 + loff + lane], hv);
  }
}

// ---------- FALLBACK gather (round-2 proven): scalar full-wave rows, uniform eid ----------
__global__ __launch_bounds__(256) void gather_k(
    const float* __restrict__ ea, const int* __restrict__ off,
    const int* __restrict__ eid, const int* __restrict__ batch,
    float* __restrict__ hbuf, float* __restrict__ gacc,
    int loff, int store_h) {
  int gid = blockIdx.x * blockDim.x + threadIdx.x;
  int w = gid >> 6, lane = gid & 63;
  int nw = (gridDim.x * blockDim.x) >> 6;
  const float* base = ea + lane;
  for (int n = w; n < NN; n += nw) {
    int s = off[n], e = off[n + 1];
    int g = batch[n];
    float a0 = 0.f, a1 = 0.f, a2 = 0.f, a3 = 0.f;
    int i = s;
    for (; i + 4 <= e; i += 4) {
      int e0 = eid[i], e1 = eid[i + 1], e2 = eid[i + 2], e3 = eid[i + 3];
      a0 += base[(size_t)e0 * 64];
      a1 += base[(size_t)e1 * 64];
      a2 += base[(size_t)e2 * 64];
      a3 += base[(size_t)e3 * 64];
    }
    for (; i < e; i++) a0 += base[(size_t)eid[i] * 64];
    float acc = (a0 + a1) + (a2 + a3);
    float hv = acc / (float)max(e - s, 1);
    if (store_h) hbuf[(size_t)n * 64 + lane] = hv;
    atomicAdd(&gacc[g * 256 + loff + lane], hv);
  }
}

// ---------- FALLBACK layer-0 pool (segmented, no permute) ----------
__global__ __launch_bounds__(256) void pool_seg_k(const float* __restrict__ ea,
                                                  const int* __restrict__ eoff,
                                                  float* __restrict__ gacc, int loff) {
  int gid = blockIdx.x * blockDim.x + threadIdx.x;
  int w = gid >> 6, lane = gid & 63;
  const int NW = (gridDim.x * blockDim.x) >> 6;
  const int CH = (NE + NW - 1) / NW;
  int r0 = w * CH, r1 = min(r0 + CH, NE);
  if (r0 >= r1) return;
  int g = 0;
  while (eoff[g + 1] <= r0) g++;
  const float* base = ea + lane;
  while (r0 < r1) {
    int gend = min(r1, eoff[g + 1]);
    float a0 = 0.f, a1 = 0.f, a2 = 0.f, a3 = 0.f;
    float a4 = 0.f, a5 = 0.f, a6 = 0.f, a7 = 0.f;
    int r = r0;
    for (; r + 8 <= gend; r += 8) {
      a0 += base[(size_t)(r + 0) * 64];
      a1 += base[(size_t)(r + 1) * 64];
      a2 += base[(size_t)(r + 2) * 64];
      a3 += base[(size_t)(r + 3) * 64];
      a4 += base[(size_t)(r + 4) * 64];
      a5 += base[(size_t)(r + 5) * 64];
      a6 += base[(size_t)(r + 6) * 64];
      a7 += base[(size_t)(r + 7) * 64];
    }
    for (; r < gend; r++) a0 += base[(size_t)r * 64];
    float s = ((a0 + a1) + (a2 + a3)) + ((a4 + a5) + (a6 + a7));
    atomicAdd(&gacc[g * 256 + loff + lane], s);
    r0 = gend;
    g++;
  }
}

// ---------- edge MLP via bf16 MFMA: ea = relu([h[row],ea]@W1+b1)@W2+b2 ----------
// Block = 256 thr (4 waves), 64 edges. LDS OVERLAY: xin / hid / fbuf share one
// 17.4KB buffer (was 35KB) -> 8 blocks/CU occupancy cap (was 4). Epilogue:
// optional ea store, fused ge-pool, and (streaming path) CSR-scatter of the
// output rows into esrt via LDS transpose (full 256B stores).
__global__ __launch_bounds__(256) void mlp_mfma_k(
    const float* hbuf, float* ea, const int* rowp,
    const u16* W1T, const float* b1,     // W1T [128n][128k] bf16
    const u16* W2T, const float* b2,     // W2T [64n][128k] bf16
    const int* ebatch, float* gacc, int loff,
    const int* pos, float* esrt, int store_ea) {
  __shared__ char smem[64 * 136 * 2];    // 17408B, overlaid buffers
  u16* xin = (u16*)smem;                 // [64][136] bf16
  u16* hid = (u16*)smem;                 // [64][136] bf16 (overlays xin)
  float* fbuf = (float*)smem;            // [64][68] f32  (overlays hid)
  const int t = threadIdx.x;
  const int e0 = blockIdx.x * 64;
  const int lane = t & 63;
  const int wave = t >> 6;
  const int m16 = lane & 15;             // fragment row/col index
  const int quad = lane >> 4;            // k-subblock

  // ---- preload B fragments (registers, straight from global; L2-hot) ----
  bf16x8 B1[2][4], B2[4];
#pragma unroll
  for (int ni = 0; ni < 2; ni++)
#pragma unroll
    for (int ki = 0; ki < 4; ki++)
      B1[ni][ki] = *(const bf16x8*)(W1T + (wave * 32 + ni * 16 + m16) * 128 + ki * 32 + quad * 8);
#pragma unroll
  for (int ki = 0; ki < 4; ki++)
    B2[ki] = *(const bf16x8*)(W2T + (wave * 16 + m16) * 128 + ki * 32 + quad * 8);

  // ---- stage xin[64][128] = [h[row[e]], ea[e]] as bf16 ----
#pragma unroll
  for (int it = 0; it < 8; it++) {
    int f = it * 256 + t;                // float4 id 0..2047
    int r = f >> 5;                      // edge row 0..63
    int c = (f & 31) * 4;                // col 0..124
    const float* src;
    if (c < 64) {
      int nd = rowp[e0 + r];
      src = hbuf + (size_t)nd * 64 + c;
    } else {
      src = ea + (size_t)(e0 + r) * 64 + (c - 64);
    }
    float4 v = *(const float4*)src;
    u32 p0 = (u32)f2bf(v.x) | ((u32)f2bf(v.y) << 16);
    u32 p1 = (u32)f2bf(v.z) | ((u32)f2bf(v.w) << 16);
    u32* dst = (u32*)&xin[r * 136 + c];
    dst[0] = p0;
    dst[1] = p1;
  }
  __syncthreads();

  // ---- GEMM1: [64x128] @ W1[128x128] -> acc1 (regs) ----
  f32x4 zero = {0.f, 0.f, 0.f, 0.f};
  f32x4 acc1[2][4];
#pragma unroll
  for (int ni = 0; ni < 2; ni++)
#pragma unroll
    for (int mi = 0; mi < 4; mi++) acc1[ni][mi] = zero;

#pragma unroll
  for (int ki = 0; ki < 4; ki++) {
#pragma unroll
    for (int mi = 0; mi < 4; mi++) {
      bf16x8 A = *(const bf16x8*)&xin[(mi * 16 + m16) * 136 + ki * 32 + quad * 8];
      acc1[0][mi] = __builtin_amdgcn_mfma_f32_16x16x32_bf16(A, B1[0][ki], acc1[0][mi], 0, 0, 0);
      acc1[1][mi] = __builtin_amdgcn_mfma_f32_16x16x32_bf16(A, B1[1][ki], acc1[1][mi], 0, 0, 0);
    }
  }
  __syncthreads();                       // all xin reads done before overwrite

  // ---- write hid (overlays xin), +bias, ReLU ----
  float b1v0 = b1[wave * 32 + m16];
  float b1v1 = b1[wave * 32 + 16 + m16];
#pragma unroll
  for (int mi = 0; mi < 4; mi++) {
#pragma unroll
    for (int reg = 0; reg < 4; reg++) {
      int r = mi * 16 + quad * 4 + reg;
      hid[r * 136 + wave * 32 + m16]      = f2bf(fmaxf(acc1[0][mi][reg] + b1v0, 0.f));
      hid[r * 136 + wave * 32 + 16 + m16] = f2bf(fmaxf(acc1[1][mi][reg] + b1v1, 0.f));
    }
  }
  __syncthreads();

  // ---- GEMM2: hid[64x128] @ W2[128x64] -> acc2 ----
  f32x4 acc2[4];
#pragma unroll
  for (int mi = 0; mi < 4; mi++) acc2[mi] = zero;
#pragma unroll
  for (int ki = 0; ki < 4; ki++) {
#pragma unroll
    for (int mi = 0; mi < 4; mi++) {
      bf16x8 A = *(const bf16x8*)&hid[(mi * 16 + m16) * 136 + ki * 32 + quad * 8];
      acc2[mi] = __builtin_amdgcn_mfma_f32_16x16x32_bf16(A, B2[ki], acc2[mi], 0, 0, 0);
    }
  }
  float b2v = b2[wave * 16 + m16];

  // ---- ea store (edge-ordered; needed as next layer's input) ----
  if (store_ea) {
#pragma unroll
    for (int mi = 0; mi < 4; mi++) {
#pragma unroll
      for (int reg = 0; reg < 4; reg++) {
        int r = mi * 16 + quad * 4 + reg;
        ea[(size_t)(e0 + r) * 64 + wave * 16 + m16] = acc2[mi][reg] + b2v;
      }
    }
  }

  // ---- fused ge pooling: sum this block's 64 output rows per graph ----
  int g0 = ebatch[e0], g1 = ebatch[e0 + 63];
  int colo = wave * 16 + m16;
  if (g0 == g1) {                        // fast path: single-graph block
    float s = 0.f;
#pragma unroll
    for (int mi = 0; mi < 4; mi++)
#pragma unroll
      for (int reg = 0; reg < 4; reg++) s += acc2[mi][reg] + b2v;
    s += __shfl_xor(s, 16);
    s += __shfl_xor(s, 32);
    if (quad == 0) atomicAdd(&gacc[g0 * 256 + loff + colo], s);
  } else {                               // boundary block (<=15 total): per-value atomics
#pragma unroll
    for (int mi = 0; mi < 4; mi++)
#pragma unroll
      for (int reg = 0; reg < 4; reg++) {
        int r = mi * 16 + quad * 4 + reg;
        atomicAdd(&gacc[ebatch[e0 + r] * 256 + loff + colo], acc2[mi][reg] + b2v);
      }
  }

  // ---- CSR scatter: esrt[pos[e]] = out row (streaming-gather feed) ----
  if (esrt) {
    __syncthreads();                     // all hid reads done before overwrite
#pragma unroll
    for (int mi = 0; mi < 4; mi++)
#pragma unroll
      for (int reg = 0; reg < 4; reg++)
        fbuf[(mi * 16 + quad * 4 + reg) * 68 + wave * 16 + m16] = acc2[mi][reg] + b2v;
    __syncthreads();
#pragma unroll
    for (int j = 0; j < 16; j++) {       // wave w handles rows 16w..16w+15
      int r = wave * 16 + j;
      int pr = pos[e0 + r];              // uniform -> scalar load
      esrt[(size_t)pr * 64 + lane] = fbuf[r * 68 + lane];   // 256B store
    }
  }
}

// ---------- finalize: means (acc already in output layout), head, f32 out ----------
__global__ __launch_bounds__(256) void finalize_k(
    const float* gn_acc, const float* ge_acc,
    const int* cnt_n, const int* cnt_e,
    const float* Wo1, const float* bo1,
    const float* Wo2, const float* bo2,
    const float* Wo3, const float* bo3,
    float* out) {
  __shared__ float attr[16][512];
  __shared__ float o1[16][128];
  __shared__ float o2[16][128];
  int t = threadIdx.x;
  for (int i = t; i < 4096; i += 256) {
    int g = i >> 8, c = i & 255;
    float vn = gn_acc[i] / (float)max(cnt_n[g], 1);
    float ve = ge_acc[i] / (float)max(cnt_e[g], 1);
    out[i] = vn;
    out[4096 + i] = ve;
    attr[g][c] = vn;
    attr[g][256 + c] = ve;
  }
  __syncthreads();
  {
    int j = t & 127, gh = t >> 7;
    float a[8];
#pragma unroll
    for (int q = 0; q < 8; q++) a[q] = bo1[j];
    for (int k = 0; k < 512; k++) {
      float w = Wo1[k * 128 + j];
#pragma unroll
      for (int q = 0; q < 8; q++) a[q] = fmaf(attr[gh * 8 + q][k], w, a[q]);
    }
#pragma unroll
    for (int q = 0; q < 8; q++) o1[gh * 8 + q][j] = fmaxf(a[q], 0.f);
  }
  __syncthreads();
  {
    int j = t & 127, gh = t >> 7;
    float a[8];
#pragma unroll
    for (int q = 0; q < 8; q++) a[q] = bo2[j];
    for (int k = 0; k < 128; k++) {
      float w = Wo2[k * 128 + j];
#pragma unroll
      for (int q = 0; q < 8; q++) a[q] = fmaf(o1[gh * 8 + q][k], w, a[q]);
    }
#pragma unroll
    for (int q = 0; q < 8; q++) o2[gh * 8 + q][j] = fmaxf(a[q], 0.f);
  }
  __syncthreads();
  {
    int j = t & 31, gb = t >> 5;
#pragma unroll
    for (int q = 0; q < 2; q++) {
      int g = gb * 2 + q;
      float a = bo3[j];
      for (int k = 0; k < 128; k++) a = fmaf(o2[g][k], Wo3[k * 32 + j], a);
      out[8192 + g * 32 + j] = a;
    }
  }
}

extern "C" void kernel_launch(void* const* d_in, const int* in_sizes, int n_in,
                              void* d_out, int out_size, void* d_ws, size_t ws_size,
                              hipStream_t stream) {
  float* ea = (float*)d_in[1];               // [NE,64] f32, updated IN-PLACE
  const int* edge_index = (const int*)d_in[3];
  const int* row = edge_index;
  const int* col = edge_index + NE;
  const int* batch = (const int*)d_in[4];
  const int* ebatch = (const int*)d_in[5];
  const float* W1s = (const float*)d_in[6];  // [3,128,128]
  const float* b1s = (const float*)d_in[7];  // [3,128]
  const float* W2s = (const float*)d_in[8];  // [3,128,64]
  const float* b2s = (const float*)d_in[9];  // [3,64]
  const float* Wo1 = (const float*)d_in[10];
  const float* bo1 = (const float*)d_in[11];
  const float* Wo2 = (const float*)d_in[12];
  const float* bo2 = (const float*)d_in[13];
  const float* Wo3 = (const float*)d_in[14];
  const float* bo3 = (const float*)d_in[15];

  char* p = (char*)d_ws;
  auto alloc = [&](size_t b) { char* r = p; p += (b + 255) & ~(size_t)255; return r; };
  // ---- zero region (one memset) ----
  int* deg = (int*)alloc(NN * 4);
  int* cursor = (int*)alloc(NN * 4);
  int* cnt_n = (int*)alloc(64);
  int* cnt_e = (int*)alloc(64);
  float* gn_acc = (float*)alloc(NGR * 256 * 4);
  float* ge_acc = (float*)alloc(NGR * 256 * 4);
  size_t zbytes = (size_t)(p - (char*)d_ws);
  // ---- non-zeroed ----
  int* csr_off = (int*)alloc((NN + 1) * 4);
  int* csr_eid = (int*)alloc((size_t)NE * 4);
  int* pos = (int*)alloc((size_t)NE * 4);
  float* hbuf = (float*)alloc((size_t)NN * 64 * 4);
  u16* W1T = (u16*)alloc(3 * 128 * 128 * 2);
  u16* W2T = (u16*)alloc(3 * 64 * 128 * 2);
  int* eoff = (int*)alloc((NGR + 1) * 4);
  // esrt: CSR-permuted edge rows (205MB) — only if workspace allows
  float* esrt = nullptr;
  {
    size_t used = (size_t)(p - (char*)d_ws);
    size_t need = (size_t)NE * 64 * 4 + 512;
    if (ws_size >= used + need) esrt = (float*)alloc((size_t)NE * 64 * 4);
  }

  hipMemsetAsync(d_ws, 0, zbytes, stream);

  prep_w_k<<<(3 * 128 * 128 + 3 * 128 * 64 + 255) / 256, 256, 0, stream>>>(W1s, W2s, W1T, W2T);
  hist_deg<<<(NE + 255) / 256, 256, 0, stream>>>(col, deg);
  count_graphs<<<1, 64, 0, stream>>>(batch, ebatch, cnt_n, cnt_e, eoff);
  scan_deg<<<1, 256, 0, stream>>>(deg, csr_off);
  fill_csr<<<(NE + 255) / 256, 256, 0, stream>>>(col, csr_off, cursor, csr_eid, pos);

  if (esrt) {
    // ---- streaming path: permute once, then all gathers are sequential ----
    pool_perm_k<<<2048, 256, 0, stream>>>(ea, eoff, pos, esrt, ge_acc, 0);
    gather_seq_k<<<2048, 256, 0, stream>>>(esrt, csr_off, batch, hbuf, gn_acc, 0, 1);
    for (int l = 0; l < 3; l++) {
      mlp_mfma_k<<<NE / 64, 256, 0, stream>>>(hbuf, ea, row,
          W1T + l * 16384, b1s + l * 128, W2T + l * 8192, b2s + l * 64,
          ebatch, ge_acc, (l + 1) * 64, pos, esrt, l < 2 ? 1 : 0);
      gather_seq_k<<<2048, 256, 0, stream>>>(esrt, csr_off, batch, hbuf,
                                             gn_acc, (l + 1) * 64, l < 2 ? 1 : 0);
    }
  } else {
    // ---- fallback (round-2 proven): random gather via uniform eid ----
    pool_seg_k<<<2048, 256, 0, stream>>>(ea, eoff, ge_acc, 0);
    gather_k<<<2048, 256, 0, stream>>>(ea, csr_off, csr_eid, batch, hbuf, gn_acc, 0, 1);
    for (int l = 0; l < 3; l++) {
      mlp_mfma_k<<<NE / 64, 256, 0, stream>>>(hbuf, ea, row,
          W1T + l * 16384, b1s + l * 128, W2T + l * 8192, b2s + l * 64,
          ebatch, ge_acc, (l + 1) * 64, pos, nullptr, 1);
      gather_k<<<2048, 256, 0, stream>>>(ea, csr_off, csr_eid, batch, hbuf,
                                         gn_acc, (l + 1) * 64, l < 2 ? 1 : 0);
    }
  }

  finalize_k<<<1, 256, 0, stream>>>(gn_acc, ge_acc, cnt_n, cnt_e,
      Wo1, bo1, Wo2, bo2, Wo3, bo3, (float*)d_out);
}

// Round 8
// 1996.208 us; speedup vs baseline: 1.3487x; 1.0811x over previous
//
#include <hip/hip_runtime.h>

#define NN 50000      // nodes
#define NE 800000     // edges
#define NGR 16        // graphs

typedef unsigned short u16;
typedef unsigned int u32;
typedef __attribute__((ext_vector_type(8))) short bf16x8;
typedef __attribute__((ext_vector_type(4))) float f32x4;

__device__ __forceinline__ u16 f2bf(float f) {       // RNE f32->bf16
  u32 u = __float_as_uint(f);
  return (u16)((u + 0x7fffu + ((u >> 16) & 1u)) >> 16);
}

// ---------- degree histogram ----------
__global__ void hist_deg(const int* col, int* deg) {
  int e = blockIdx.x * blockDim.x + threadIdx.x;
  if (e < NE) atomicAdd(&deg[col[e]], 1);
}

// ---------- per-graph counts (sorted ids) + edge segment offsets ----------
__device__ int lbound(const int* a, int n, int v) {
  int lo = 0, hi = n;
  while (lo < hi) { int m = (lo + hi) >> 1; if (a[m] < v) lo = m + 1; else hi = m; }
  return lo;
}
__global__ void count_graphs(const int* batch, const int* ebatch, int* cnt_n, int* cnt_e,
                             int* eoff) {
  int t = threadIdx.x;
  if (t < NGR) cnt_n[t] = lbound(batch, NN, t + 1) - lbound(batch, NN, t);
  else if (t < 2 * NGR) { int g = t - NGR; cnt_e[g] = lbound(ebatch, NE, g + 1) - lbound(ebatch, NE, g); }
  else if (t < 3 * NGR + 1) { int g = t - 2 * NGR; eoff[g] = lbound(ebatch, NE, g); }  // eoff[16]=NE
}

// ---------- exclusive scan of deg -> csr_off (single block) ----------
__global__ __launch_bounds__(256) void scan_deg(const int* deg, int* off) {
  __shared__ int sums[256];
  const int CH = (NN + 255) / 256;
  int t = threadIdx.x;
  int base = t * CH;
  int s = 0;
  for (int i = 0; i < CH; i++) { int idx = base + i; if (idx < NN) s += deg[idx]; }
  sums[t] = s;
  __syncthreads();
  for (int d = 1; d < 256; d <<= 1) {
    int v = (t >= d) ? sums[t - d] : 0;
    __syncthreads();
    sums[t] += v;
    __syncthreads();
  }
  int run = (t == 0) ? 0 : sums[t - 1];
  for (int i = 0; i < CH; i++) { int idx = base + i; if (idx < NN) { off[idx] = run; run += deg[idx]; } }
  if (t == 255) off[NN] = run;
}

// ---------- CSR fill: eid, pos, and CSR-ordered row/graph tables ----------
__global__ void fill_csr(const int* col, const int* rowp, const int* ebatch,
                         const int* off, int* cursor, int* eid, int* pos,
                         int* rowsrt, int* ebs) {
  int e = blockIdx.x * blockDim.x + threadIdx.x;
  if (e < NE) {
    int c = col[e];
    int p = atomicAdd(&cursor[c], 1);
    int slot = off[c] + p;
    eid[slot] = e;
    pos[e] = slot;
    rowsrt[slot] = rowp[e];
    ebs[slot] = ebatch[e];
  }
}

// ---------- weights f32 -> bf16 TRANSPOSED (W1T[l][n][k], W2T[l][n][k]) ----------
__global__ void prep_w_k(const float* W1, const float* W2, u16* W1T, u16* W2T) {
  int i = blockIdx.x * 256 + threadIdx.x;
  if (i < 3 * 128 * 128) {
    int l = i / 16384, k = (i >> 7) & 127, n = i & 127;
    W1T[l * 16384 + n * 128 + k] = f2bf(W1[i]);
  } else {
    int j = i - 3 * 128 * 128;
    if (j < 3 * 128 * 64) {
      int l = j / 8192, k = (j >> 6) & 127, n = j & 63;
      W2T[l * 8192 + n * 128 + k] = f2bf(W2[j]);
    }
  }
}

// ---------- layer-0: segmented ge pool + CSR permute (esrt[pos[e]] = ea[e]) ----------
__global__ __launch_bounds__(256) void pool_perm_k(const float* __restrict__ ea,
                                                   const int* __restrict__ eoff,
                                                   const int* __restrict__ pos,
                                                   float* __restrict__ esrt,
                                                   float* __restrict__ gacc, int loff) {
  int gid = blockIdx.x * blockDim.x + threadIdx.x;
  int w = gid >> 6, lane = gid & 63;
  const int NW = (gridDim.x * blockDim.x) >> 6;
  const int CH = (NE + NW - 1) / NW;
  int r0 = w * CH, r1 = min(r0 + CH, NE);
  if (r0 >= r1) return;
  int g = 0;
  while (eoff[g + 1] <= r0) g++;       // <=16 scalar iters, once per wave
  const float* base = ea + lane;
  float* sbase = esrt + lane;
  while (r0 < r1) {
    int gend = min(r1, eoff[g + 1]);
    float a0 = 0.f, a1 = 0.f, a2 = 0.f, a3 = 0.f;
    float a4 = 0.f, a5 = 0.f, a6 = 0.f, a7 = 0.f;
    int r = r0;
    for (; r + 8 <= gend; r += 8) {
      float v0 = base[(size_t)(r + 0) * 64];
      float v1 = base[(size_t)(r + 1) * 64];
      float v2 = base[(size_t)(r + 2) * 64];
      float v3 = base[(size_t)(r + 3) * 64];
      float v4 = base[(size_t)(r + 4) * 64];
      float v5 = base[(size_t)(r + 5) * 64];
      float v6 = base[(size_t)(r + 6) * 64];
      float v7 = base[(size_t)(r + 7) * 64];
      sbase[(size_t)pos[r + 0] * 64] = v0;
      sbase[(size_t)pos[r + 1] * 64] = v1;
      sbase[(size_t)pos[r + 2] * 64] = v2;
      sbase[(size_t)pos[r + 3] * 64] = v3;
      sbase[(size_t)pos[r + 4] * 64] = v4;
      sbase[(size_t)pos[r + 5] * 64] = v5;
      sbase[(size_t)pos[r + 6] * 64] = v6;
      sbase[(size_t)pos[r + 7] * 64] = v7;
      a0 += v0; a1 += v1; a2 += v2; a3 += v3;
      a4 += v4; a5 += v5; a6 += v6; a7 += v7;
    }
    for (; r < gend; r++) {
      float v = base[(size_t)r * 64];
      sbase[(size_t)pos[r] * 64] = v;
      a0 += v;
    }
    float s = ((a0 + a1) + (a2 + a3)) + ((a4 + a5) + (a6 + a7));
    atomicAdd(&gacc[g * 256 + loff + lane], s);
    r0 = gend;
    g++;
  }
}

// ---------- STREAMING gather, CHUNKED: wave owns contiguous node range ----------
// Reads one long sequential esrt stream per wave; per-graph register pooling
// (nodes sorted by batch) -> ~1 gacc atomic per wave instead of per node.
__global__ __launch_bounds__(256) void gather_seq_k(
    const float* __restrict__ esrt, const int* __restrict__ off,
    const int* __restrict__ batch, float* __restrict__ hbuf,
    float* __restrict__ gacc, int loff, int store_h) {
  int gid = blockIdx.x * blockDim.x + threadIdx.x;
  int w = gid >> 6, lane = gid & 63;
  const int NW = (gridDim.x * blockDim.x) >> 6;
  const int CHN = (NN + NW - 1) / NW;
  int n0 = w * CHN, n1 = min(n0 + CHN, NN);
  if (n0 >= n1) return;
  const float* base = esrt + lane;
  int cg = batch[n0];
  float gsum = 0.f;
  for (int n = n0; n < n1; n++) {
    int s = off[n], e = off[n + 1];
    float a0 = 0.f, a1 = 0.f, a2 = 0.f, a3 = 0.f;
    float a4 = 0.f, a5 = 0.f, a6 = 0.f, a7 = 0.f;
    int i = s;
    for (; i + 8 <= e; i += 8) {
      a0 += base[(size_t)(i + 0) * 64];
      a1 += base[(size_t)(i + 1) * 64];
      a2 += base[(size_t)(i + 2) * 64];
      a3 += base[(size_t)(i + 3) * 64];
      a4 += base[(size_t)(i + 4) * 64];
      a5 += base[(size_t)(i + 5) * 64];
      a6 += base[(size_t)(i + 6) * 64];
      a7 += base[(size_t)(i + 7) * 64];
    }
    for (; i + 4 <= e; i += 4) {
      a0 += base[(size_t)(i + 0) * 64];
      a1 += base[(size_t)(i + 1) * 64];
      a2 += base[(size_t)(i + 2) * 64];
      a3 += base[(size_t)(i + 3) * 64];
    }
    for (; i < e; i++) a0 += base[(size_t)i * 64];
    float acc = ((a0 + a1) + (a2 + a3)) + ((a4 + a5) + (a6 + a7));
    float hv = acc / (float)max(e - s, 1);
    if (store_h) hbuf[(size_t)n * 64 + lane] = hv;
    int g = batch[n];                   // uniform scalar load
    if (g != cg) {
      atomicAdd(&gacc[cg * 256 + loff + lane], gsum);
      gsum = 0.f;
      cg = g;
    }
    gsum += hv;
  }
  atomicAdd(&gacc[cg * 256 + loff + lane], gsum);
}

// ---------- CSR-ordered edge MLP: esrt[i] = relu([h[rowsrt[i]],esrt[i]]@W1+b1)@W2+b2 ----------
// Sequential esrt read + in-place sequential write (no ea, no scatter).
// ge-pool via per-block LDS bins (graph ids unsorted in CSR order); nonzero-only
// flush -> ~64 atomics for single-graph blocks.
__global__ __launch_bounds__(256) void mlp_csr_k(
    const float* __restrict__ hbuf, float* __restrict__ esrt,
    const int* __restrict__ rowsrt, const int* __restrict__ ebs,
    const u16* __restrict__ W1T, const float* __restrict__ b1,
    const u16* __restrict__ W2T, const float* __restrict__ b2,
    float* __restrict__ gacc, int loff) {
  __shared__ u16 sh[64 * 136];           // 17408B: xin overlays hid
  __shared__ float lacc[NGR * 64];       // 4KB ge-pool bins
  u16* xin = sh;
  u16* hid = sh;
  const int t = threadIdx.x;
  const int e0 = blockIdx.x * 64;
  const int lane = t & 63;
  const int wave = t >> 6;
  const int m16 = lane & 15;
  const int quad = lane >> 4;

#pragma unroll
  for (int i = 0; i < 4; i++) lacc[t + 256 * i] = 0.f;

  // ---- preload B fragments ----
  bf16x8 B1[2][4], B2[4];
#pragma unroll
  for (int ni = 0; ni < 2; ni++)
#pragma unroll
    for (int ki = 0; ki < 4; ki++)
      B1[ni][ki] = *(const bf16x8*)(W1T + (wave * 32 + ni * 16 + m16) * 128 + ki * 32 + quad * 8);
#pragma unroll
  for (int ki = 0; ki < 4; ki++)
    B2[ki] = *(const bf16x8*)(W2T + (wave * 16 + m16) * 128 + ki * 32 + quad * 8);

  // ---- stage xin[64][128] = [hbuf[rowsrt[i]], esrt[i]] as bf16 ----
#pragma unroll
  for (int it = 0; it < 8; it++) {
    int f = it * 256 + t;
    int r = f >> 5;
    int c = (f & 31) * 4;
    const float* src;
    if (c < 64) {
      src = hbuf + (size_t)rowsrt[e0 + r] * 64 + c;
    } else {
      src = esrt + (size_t)(e0 + r) * 64 + (c - 64);
    }
    float4 v = *(const float4*)src;
    u32 p0 = (u32)f2bf(v.x) | ((u32)f2bf(v.y) << 16);
    u32 p1 = (u32)f2bf(v.z) | ((u32)f2bf(v.w) << 16);
    u32* dst = (u32*)&xin[r * 136 + c];
    dst[0] = p0;
    dst[1] = p1;
  }
  __syncthreads();

  // ---- GEMM1 -> acc1 (regs) ----
  f32x4 zero = {0.f, 0.f, 0.f, 0.f};
  f32x4 acc1[2][4];
#pragma unroll
  for (int ni = 0; ni < 2; ni++)
#pragma unroll
    for (int mi = 0; mi < 4; mi++) acc1[ni][mi] = zero;
#pragma unroll
  for (int ki = 0; ki < 4; ki++) {
#pragma unroll
    for (int mi = 0; mi < 4; mi++) {
      bf16x8 A = *(const bf16x8*)&xin[(mi * 16 + m16) * 136 + ki * 32 + quad * 8];
      acc1[0][mi] = __builtin_amdgcn_mfma_f32_16x16x32_bf16(A, B1[0][ki], acc1[0][mi], 0, 0, 0);
      acc1[1][mi] = __builtin_amdgcn_mfma_f32_16x16x32_bf16(A, B1[1][ki], acc1[1][mi], 0, 0, 0);
    }
  }
  __syncthreads();                       // xin reads done before hid overwrite

  float b1v0 = b1[wave * 32 + m16];
  float b1v1 = b1[wave * 32 + 16 + m16];
#pragma unroll
  for (int mi = 0; mi < 4; mi++) {
#pragma unroll
    for (int reg = 0; reg < 4; reg++) {
      int r = mi * 16 + quad * 4 + reg;
      hid[r * 136 + wave * 32 + m16]      = f2bf(fmaxf(acc1[0][mi][reg] + b1v0, 0.f));
      hid[r * 136 + wave * 32 + 16 + m16] = f2bf(fmaxf(acc1[1][mi][reg] + b1v1, 0.f));
    }
  }
  __syncthreads();

  // ---- GEMM2 -> acc2 ----
  f32x4 acc2[4];
#pragma unroll
  for (int mi = 0; mi < 4; mi++) acc2[mi] = zero;
#pragma unroll
  for (int ki = 0; ki < 4; ki++) {
#pragma unroll
    for (int mi = 0; mi < 4; mi++) {
      bf16x8 A = *(const bf16x8*)&hid[(mi * 16 + m16) * 136 + ki * 32 + quad * 8];
      acc2[mi] = __builtin_amdgcn_mfma_f32_16x16x32_bf16(A, B2[ki], acc2[mi], 0, 0, 0);
    }
  }
  float b2v = b2[wave * 16 + m16];
  int colo = wave * 16 + m16;

  // ---- in-place esrt write + LDS ge-pool binning ----
#pragma unroll
  for (int mi = 0; mi < 4; mi++) {
#pragma unroll
    for (int reg = 0; reg < 4; reg++) {
      int r = mi * 16 + quad * 4 + reg;
      float v = acc2[mi][reg] + b2v;
      esrt[(size_t)(e0 + r) * 64 + colo] = v;
      atomicAdd(&lacc[ebs[e0 + r] * 64 + colo], v);
    }
  }
  __syncthreads();
#pragma unroll
  for (int i = 0; i < 4; i++) {
    int idx = t + 256 * i;               // g = idx>>6, col = idx&63
    float v = lacc[idx];
    if (v != 0.f) atomicAdd(&gacc[(idx >> 6) * 256 + loff + (idx & 63)], v);
  }
}

// ---------- FALLBACK kernels (round-2 proven path, used only if ws too small) ----------
__global__ __launch_bounds__(256) void gather_k(
    const float* __restrict__ ea, const int* __restrict__ off,
    const int* __restrict__ eid, const int* __restrict__ batch,
    float* __restrict__ hbuf, float* __restrict__ gacc,
    int loff, int store_h) {
  int gid = blockIdx.x * blockDim.x + threadIdx.x;
  int w = gid >> 6, lane = gid & 63;
  int nw = (gridDim.x * blockDim.x) >> 6;
  const float* base = ea + lane;
  for (int n = w; n < NN; n += nw) {
    int s = off[n], e = off[n + 1];
    int g = batch[n];
    float a0 = 0.f, a1 = 0.f, a2 = 0.f, a3 = 0.f;
    int i = s;
    for (; i + 4 <= e; i += 4) {
      int e0 = eid[i], e1 = eid[i + 1], e2 = eid[i + 2], e3 = eid[i + 3];
      a0 += base[(size_t)e0 * 64];
      a1 += base[(size_t)e1 * 64];
      a2 += base[(size_t)e2 * 64];
      a3 += base[(size_t)e3 * 64];
    }
    for (; i < e; i++) a0 += base[(size_t)eid[i] * 64];
    float acc = (a0 + a1) + (a2 + a3);
    float hv = acc / (float)max(e - s, 1);
    if (store_h) hbuf[(size_t)n * 64 + lane] = hv;
    atomicAdd(&gacc[g * 256 + loff + lane], hv);
  }
}

__global__ __launch_bounds__(256) void pool_seg_k(const float* __restrict__ ea,
                                                  const int* __restrict__ eoff,
                                                  float* __restrict__ gacc, int loff) {
  int gid = blockIdx.x * blockDim.x + threadIdx.x;
  int w = gid >> 6, lane = gid & 63;
  const int NW = (gridDim.x * blockDim.x) >> 6;
  const int CH = (NE + NW - 1) / NW;
  int r0 = w * CH, r1 = min(r0 + CH, NE);
  if (r0 >= r1) return;
  int g = 0;
  while (eoff[g + 1] <= r0) g++;
  const float* base = ea + lane;
  while (r0 < r1) {
    int gend = min(r1, eoff[g + 1]);
    float a0 = 0.f, a1 = 0.f, a2 = 0.f, a3 = 0.f;
    float a4 = 0.f, a5 = 0.f, a6 = 0.f, a7 = 0.f;
    int r = r0;
    for (; r + 8 <= gend; r += 8) {
      a0 += base[(size_t)(r + 0) * 64];
      a1 += base[(size_t)(r + 1) * 64];
      a2 += base[(size_t)(r + 2) * 64];
      a3 += base[(size_t)(r + 3) * 64];
      a4 += base[(size_t)(r + 4) * 64];
      a5 += base[(size_t)(r + 5) * 64];
      a6 += base[(size_t)(r + 6) * 64];
      a7 += base[(size_t)(r + 7) * 64];
    }
    for (; r < gend; r++) a0 += base[(size_t)r * 64];
    float s = ((a0 + a1) + (a2 + a3)) + ((a4 + a5) + (a6 + a7));
    atomicAdd(&gacc[g * 256 + loff + lane], s);
    r0 = gend;
    g++;
  }
}

__global__ __launch_bounds__(256) void mlp_fallback_k(
    const float* hbuf, float* ea, const int* rowp,
    const u16* W1T, const float* b1,
    const u16* W2T, const float* b2,
    const int* ebatch, float* gacc, int loff) {
  __shared__ u16 sh[2 * 64 * 136];
  u16* xin = sh;
  u16* hid = sh + 64 * 136;
  const int t = threadIdx.x;
  const int e0 = blockIdx.x * 64;
  const int lane = t & 63;
  const int wave = t >> 6;
  const int m16 = lane & 15;
  const int quad = lane >> 4;

  bf16x8 B1[2][4], B2[4];
#pragma unroll
  for (int ni = 0; ni < 2; ni++)
#pragma unroll
    for (int ki = 0; ki < 4; ki++)
      B1[ni][ki] = *(const bf16x8*)(W1T + (wave * 32 + ni * 16 + m16) * 128 + ki * 32 + quad * 8);
#pragma unroll
  for (int ki = 0; ki < 4; ki++)
    B2[ki] = *(const bf16x8*)(W2T + (wave * 16 + m16) * 128 + ki * 32 + quad * 8);

#pragma unroll
  for (int it = 0; it < 8; it++) {
    int f = it * 256 + t;
    int r = f >> 5;
    int c = (f & 31) * 4;
    const float* src;
    if (c < 64) {
      int nd = rowp[e0 + r];
      src = hbuf + (size_t)nd * 64 + c;
    } else {
      src = ea + (size_t)(e0 + r) * 64 + (c - 64);
    }
    float4 v = *(const float4*)src;
    u32 p0 = (u32)f2bf(v.x) | ((u32)f2bf(v.y) << 16);
    u32 p1 = (u32)f2bf(v.z) | ((u32)f2bf(v.w) << 16);
    u32* dst = (u32*)&xin[r * 136 + c];
    dst[0] = p0;
    dst[1] = p1;
  }
  __syncthreads();

  f32x4 zero = {0.f, 0.f, 0.f, 0.f};
  f32x4 acc1[2][4];
#pragma unroll
  for (int ni = 0; ni < 2; ni++)
#pragma unroll
    for (int mi = 0; mi < 4; mi++) acc1[ni][mi] = zero;
#pragma unroll
  for (int ki = 0; ki < 4; ki++) {
#pragma unroll
    for (int mi = 0; mi < 4; mi++) {
      bf16x8 A = *(const bf16x8*)&xin[(mi * 16 + m16) * 136 + ki * 32 + quad * 8];
      acc1[0][mi] = __builtin_amdgcn_mfma_f32_16x16x32_bf16(A, B1[0][ki], acc1[0][mi], 0, 0, 0);
      acc1[1][mi] = __builtin_amdgcn_mfma_f32_16x16x32_bf16(A, B1[1][ki], acc1[1][mi], 0, 0, 0);
    }
  }
  float b1v0 = b1[wave * 32 + m16];
  float b1v1 = b1[wave * 32 + 16 + m16];
#pragma unroll
  for (int mi = 0; mi < 4; mi++) {
#pragma unroll
    for (int reg = 0; reg < 4; reg++) {
      int r = mi * 16 + quad * 4 + reg;
      hid[r * 136 + wave * 32 + m16]      = f2bf(fmaxf(acc1[0][mi][reg] + b1v0, 0.f));
      hid[r * 136 + wave * 32 + 16 + m16] = f2bf(fmaxf(acc1[1][mi][reg] + b1v1, 0.f));
    }
  }
  __syncthreads();

  f32x4 acc2[4];
#pragma unroll
  for (int mi = 0; mi < 4; mi++) acc2[mi] = zero;
#pragma unroll
  for (int ki = 0; ki < 4; ki++) {
#pragma unroll
    for (int mi = 0; mi < 4; mi++) {
      bf16x8 A = *(const bf16x8*)&hid[(mi * 16 + m16) * 136 + ki * 32 + quad * 8];
      acc2[mi] = __builtin_amdgcn_mfma_f32_16x16x32_bf16(A, B2[ki], acc2[mi], 0, 0, 0);
    }
  }
  float b2v = b2[wave * 16 + m16];
#pragma unroll
  for (int mi = 0; mi < 4; mi++) {
#pragma unroll
    for (int reg = 0; reg < 4; reg++) {
      int r = mi * 16 + quad * 4 + reg;
      ea[(size_t)(e0 + r) * 64 + wave * 16 + m16] = acc2[mi][reg] + b2v;
    }
  }
  int g0 = ebatch[e0], g1 = ebatch[e0 + 63];
  int colo = wave * 16 + m16;
  if (g0 == g1) {
    float s = 0.f;
#pragma unroll
    for (int mi = 0; mi < 4; mi++)
#pragma unroll
      for (int reg = 0; reg < 4; reg++) s += acc2[mi][reg] + b2v;
    s += __shfl_xor(s, 16);
    s += __shfl_xor(s, 32);
    if (quad == 0) atomicAdd(&gacc[g0 * 256 + loff + colo], s);
  } else {
#pragma unroll
    for (int mi = 0; mi < 4; mi++)
#pragma unroll
      for (int reg = 0; reg < 4; reg++) {
        int r = mi * 16 + quad * 4 + reg;
        atomicAdd(&gacc[ebatch[e0 + r] * 256 + loff + colo], acc2[mi][reg] + b2v);
      }
  }
}

// ---------- finalize: means (acc already in output layout), head, f32 out ----------
__global__ __launch_bounds__(256) void finalize_k(
    const float* gn_acc, const float* ge_acc,
    const int* cnt_n, const int* cnt_e,
    const float* Wo1, const float* bo1,
    const float* Wo2, const float* bo2,
    const float* Wo3, const float* bo3,
    float* out) {
  __shared__ float attr[16][512];
  __shared__ float o1[16][128];
  __shared__ float o2[16][128];
  int t = threadIdx.x;
  for (int i = t; i < 4096; i += 256) {
    int g = i >> 8, c = i & 255;
    float vn = gn_acc[i] / (float)max(cnt_n[g], 1);
    float ve = ge_acc[i] / (float)max(cnt_e[g], 1);
    out[i] = vn;
    out[4096 + i] = ve;
    attr[g][c] = vn;
    attr[g][256 + c] = ve;
  }
  __syncthreads();
  {
    int j = t & 127, gh = t >> 7;
    float a[8];
#pragma unroll
    for (int q = 0; q < 8; q++) a[q] = bo1[j];
    for (int k = 0; k < 512; k++) {
      float w = Wo1[k * 128 + j];
#pragma unroll
      for (int q = 0; q < 8; q++) a[q] = fmaf(attr[gh * 8 + q][k], w, a[q]);
    }
#pragma unroll
    for (int q = 0; q < 8; q++) o1[gh * 8 + q][j] = fmaxf(a[q], 0.f);
  }
  __syncthreads();
  {
    int j = t & 127, gh = t >> 7;
    float a[8];
#pragma unroll
    for (int q = 0; q < 8; q++) a[q] = bo2[j];
    for (int k = 0; k < 128; k++) {
      float w = Wo2[k * 128 + j];
#pragma unroll
      for (int q = 0; q < 8; q++) a[q] = fmaf(o1[gh * 8 + q][k], w, a[q]);
    }
#pragma unroll
    for (int q = 0; q < 8; q++) o2[gh * 8 + q][j] = fmaxf(a[q], 0.f);
  }
  __syncthreads();
  {
    int j = t & 31, gb = t >> 5;
#pragma unroll
    for (int q = 0; q < 2; q++) {
      int g = gb * 2 + q;
      float a = bo3[j];
      for (int k = 0; k < 128; k++) a = fmaf(o2[g][k], Wo3[k * 32 + j], a);
      out[8192 + g * 32 + j] = a;
    }
  }
}

extern "C" void kernel_launch(void* const* d_in, const int* in_sizes, int n_in,
                              void* d_out, int out_size, void* d_ws, size_t ws_size,
                              hipStream_t stream) {
  float* ea = (float*)d_in[1];               // [NE,64] f32
  const int* edge_index = (const int*)d_in[3];
  const int* row = edge_index;
  const int* col = edge_index + NE;
  const int* batch = (const int*)d_in[4];
  const int* ebatch = (const int*)d_in[5];
  const float* W1s = (const float*)d_in[6];  // [3,128,128]
  const float* b1s = (const float*)d_in[7];  // [3,128]
  const float* W2s = (const float*)d_in[8];  // [3,128,64]
  const float* b2s = (const float*)d_in[9];  // [3,64]
  const float* Wo1 = (const float*)d_in[10];
  const float* bo1 = (const float*)d_in[11];
  const float* Wo2 = (const float*)d_in[12];
  const float* bo2 = (const float*)d_in[13];
  const float* Wo3 = (const float*)d_in[14];
  const float* bo3 = (const float*)d_in[15];

  char* p = (char*)d_ws;
  auto alloc = [&](size_t b) { char* r = p; p += (b + 255) & ~(size_t)255; return r; };
  // ---- zero region (one memset) ----
  int* deg = (int*)alloc(NN * 4);
  int* cursor = (int*)alloc(NN * 4);
  int* cnt_n = (int*)alloc(64);
  int* cnt_e = (int*)alloc(64);
  float* gn_acc = (float*)alloc(NGR * 256 * 4);
  float* ge_acc = (float*)alloc(NGR * 256 * 4);
  size_t zbytes = (size_t)(p - (char*)d_ws);
  // ---- non-zeroed ----
  int* csr_off = (int*)alloc((NN + 1) * 4);
  int* csr_eid = (int*)alloc((size_t)NE * 4);
  int* pos = (int*)alloc((size_t)NE * 4);
  int* rowsrt = (int*)alloc((size_t)NE * 4);
  int* ebs = (int*)alloc((size_t)NE * 4);
  float* hbuf = (float*)alloc((size_t)NN * 64 * 4);
  u16* W1T = (u16*)alloc(3 * 128 * 128 * 2);
  u16* W2T = (u16*)alloc(3 * 64 * 128 * 2);
  int* eoff = (int*)alloc((NGR + 1) * 4);
  // esrt: CSR-permuted edge rows (205MB) — only if workspace allows
  float* esrt = nullptr;
  {
    size_t used = (size_t)(p - (char*)d_ws);
    size_t need = (size_t)NE * 64 * 4 + 512;
    if (ws_size >= used + need) esrt = (float*)alloc((size_t)NE * 64 * 4);
  }

  hipMemsetAsync(d_ws, 0, zbytes, stream);

  prep_w_k<<<(3 * 128 * 128 + 3 * 128 * 64 + 255) / 256, 256, 0, stream>>>(W1s, W2s, W1T, W2T);
  hist_deg<<<(NE + 255) / 256, 256, 0, stream>>>(col, deg);
  count_graphs<<<1, 64, 0, stream>>>(batch, ebatch, cnt_n, cnt_e, eoff);
  scan_deg<<<1, 256, 0, stream>>>(deg, csr_off);
  fill_csr<<<(NE + 255) / 256, 256, 0, stream>>>(col, row, ebatch, csr_off, cursor,
                                                 csr_eid, pos, rowsrt, ebs);

  if (esrt) {
    // ---- CSR-native path: permute once; everything else is sequential ----
    pool_perm_k<<<2048, 256, 0, stream>>>(ea, eoff, pos, esrt, ge_acc, 0);
    gather_seq_k<<<2048, 256, 0, stream>>>(esrt, csr_off, batch, hbuf, gn_acc, 0, 1);
    for (int l = 0; l < 3; l++) {
      mlp_csr_k<<<NE / 64, 256, 0, stream>>>(hbuf, esrt, rowsrt, ebs,
          W1T + l * 16384, b1s + l * 128, W2T + l * 8192, b2s + l * 64,
          ge_acc, (l + 1) * 64);
      gather_seq_k<<<2048, 256, 0, stream>>>(esrt, csr_off, batch, hbuf,
                                             gn_acc, (l + 1) * 64, l < 2 ? 1 : 0);
    }
  } else {
    // ---- fallback (round-2 proven): random gather via uniform eid ----
    pool_seg_k<<<2048, 256, 0, stream>>>(ea, eoff, ge_acc, 0);
    gather_k<<<2048, 256, 0, stream>>>(ea, csr_off, csr_eid, batch, hbuf, gn_acc, 0, 1);
    for (int l = 0; l < 3; l++) {
      mlp_fallback_k<<<NE / 64, 256, 0, stream>>>(hbuf, ea, row,
          W1T + l * 16384, b1s + l * 128, W2T + l * 8192, b2s + l * 64,
          ebatch, ge_acc, (l + 1) * 64);
      gather_k<<<2048, 256, 0, stream>>>(ea, csr_off, csr_eid, batch, hbuf,
                                         gn_acc, (l + 1) * 64, l < 2 ? 1 : 0);
    }
  }

  finalize_k<<<1, 256, 0, stream>>>(gn_acc, ge_acc, cnt_n, cnt_e,
      Wo1, bo1, Wo2, bo2, Wo3, bo3, (float*)d_out);
}

// Round 9
// 1936.855 us; speedup vs baseline: 1.3900x; 1.0306x over previous
//
#include <hip/hip_runtime.h>

#define NN 50000      // nodes
#define NE 800000     // edges
#define NGR 16        // graphs

typedef unsigned short u16;
typedef unsigned int u32;
typedef __attribute__((ext_vector_type(8))) short bf16x8;
typedef __attribute__((ext_vector_type(4))) float f32x4;

__device__ __forceinline__ u16 f2bf(float f) {       // RNE f32->bf16
  u32 u = __float_as_uint(f);
  return (u16)((u + 0x7fffu + ((u >> 16) & 1u)) >> 16);
}

// ---------- degree histogram ----------
__global__ void hist_deg(const int* col, int* deg) {
  int e = blockIdx.x * blockDim.x + threadIdx.x;
  if (e < NE) atomicAdd(&deg[col[e]], 1);
}

// ---------- per-graph counts (sorted ids) + edge segment offsets ----------
__device__ int lbound(const int* a, int n, int v) {
  int lo = 0, hi = n;
  while (lo < hi) { int m = (lo + hi) >> 1; if (a[m] < v) lo = m + 1; else hi = m; }
  return lo;
}
__global__ void count_graphs(const int* batch, const int* ebatch, int* cnt_n, int* cnt_e,
                             int* eoff) {
  int t = threadIdx.x;
  if (t < NGR) cnt_n[t] = lbound(batch, NN, t + 1) - lbound(batch, NN, t);
  else if (t < 2 * NGR) { int g = t - NGR; cnt_e[g] = lbound(ebatch, NE, g + 1) - lbound(ebatch, NE, g); }
  else if (t < 3 * NGR + 1) { int g = t - 2 * NGR; eoff[g] = lbound(ebatch, NE, g); }  // eoff[16]=NE
}

// ---------- exclusive scan of deg -> csr_off (single block) ----------
__global__ __launch_bounds__(256) void scan_deg(const int* deg, int* off) {
  __shared__ int sums[256];
  const int CH = (NN + 255) / 256;
  int t = threadIdx.x;
  int base = t * CH;
  int s = 0;
  for (int i = 0; i < CH; i++) { int idx = base + i; if (idx < NN) s += deg[idx]; }
  sums[t] = s;
  __syncthreads();
  for (int d = 1; d < 256; d <<= 1) {
    int v = (t >= d) ? sums[t - d] : 0;
    __syncthreads();
    sums[t] += v;
    __syncthreads();
  }
  int run = (t == 0) ? 0 : sums[t - 1];
  for (int i = 0; i < CH; i++) { int idx = base + i; if (idx < NN) { off[idx] = run; run += deg[idx]; } }
  if (t == 255) off[NN] = run;
}

// ---------- CSR fill: eid, pos, and CSR-ordered row/graph tables ----------
__global__ void fill_csr(const int* col, const int* rowp, const int* ebatch,
                         const int* off, int* cursor, int* eid, int* pos,
                         int* rowsrt, int* ebs) {
  int e = blockIdx.x * blockDim.x + threadIdx.x;
  if (e < NE) {
    int c = col[e];
    int p = atomicAdd(&cursor[c], 1);
    int slot = off[c] + p;
    eid[slot] = e;
    pos[e] = slot;
    rowsrt[slot] = rowp[e];
    ebs[slot] = ebatch[e];
  }
}

// ---------- weights f32 -> bf16 TRANSPOSED (W1T[l][n][k], W2T[l][n][k]) ----------
__global__ void prep_w_k(const float* W1, const float* W2, u16* W1T, u16* W2T) {
  int i = blockIdx.x * 256 + threadIdx.x;
  if (i < 3 * 128 * 128) {
    int l = i / 16384, k = (i >> 7) & 127, n = i & 127;
    W1T[l * 16384 + n * 128 + k] = f2bf(W1[i]);
  } else {
    int j = i - 3 * 128 * 128;
    if (j < 3 * 128 * 64) {
      int l = j / 8192, k = (j >> 6) & 127, n = j & 63;
      W2T[l * 8192 + n * 128 + k] = f2bf(W2[j]);
    }
  }
}

// ---------- layer-0: segmented ge pool + CSR permute (esrt[pos[e]] = ea[e]) ----------
__global__ __launch_bounds__(256) void pool_perm_k(const float* __restrict__ ea,
                                                   const int* __restrict__ eoff,
                                                   const int* __restrict__ pos,
                                                   float* __restrict__ esrt,
                                                   float* __restrict__ gacc, int loff) {
  int gid = blockIdx.x * blockDim.x + threadIdx.x;
  int w = gid >> 6, lane = gid & 63;
  const int NW = (gridDim.x * blockDim.x) >> 6;
  const int CH = (NE + NW - 1) / NW;
  int r0 = w * CH, r1 = min(r0 + CH, NE);
  if (r0 >= r1) return;
  int g = 0;
  while (eoff[g + 1] <= r0) g++;       // <=16 scalar iters, once per wave
  const float* base = ea + lane;
  float* sbase = esrt + lane;
  while (r0 < r1) {
    int gend = min(r1, eoff[g + 1]);
    float a0 = 0.f, a1 = 0.f, a2 = 0.f, a3 = 0.f;
    float a4 = 0.f, a5 = 0.f, a6 = 0.f, a7 = 0.f;
    int r = r0;
    for (; r + 8 <= gend; r += 8) {
      float v0 = base[(size_t)(r + 0) * 64];
      float v1 = base[(size_t)(r + 1) * 64];
      float v2 = base[(size_t)(r + 2) * 64];
      float v3 = base[(size_t)(r + 3) * 64];
      float v4 = base[(size_t)(r + 4) * 64];
      float v5 = base[(size_t)(r + 5) * 64];
      float v6 = base[(size_t)(r + 6) * 64];
      float v7 = base[(size_t)(r + 7) * 64];
      sbase[(size_t)pos[r + 0] * 64] = v0;
      sbase[(size_t)pos[r + 1] * 64] = v1;
      sbase[(size_t)pos[r + 2] * 64] = v2;
      sbase[(size_t)pos[r + 3] * 64] = v3;
      sbase[(size_t)pos[r + 4] * 64] = v4;
      sbase[(size_t)pos[r + 5] * 64] = v5;
      sbase[(size_t)pos[r + 6] * 64] = v6;
      sbase[(size_t)pos[r + 7] * 64] = v7;
      a0 += v0; a1 += v1; a2 += v2; a3 += v3;
      a4 += v4; a5 += v5; a6 += v6; a7 += v7;
    }
    for (; r < gend; r++) {
      float v = base[(size_t)r * 64];
      sbase[(size_t)pos[r] * 64] = v;
      a0 += v;
    }
    float s = ((a0 + a1) + (a2 + a3)) + ((a4 + a5) + (a6 + a7));
    atomicAdd(&gacc[g * 256 + loff + lane], s);
    r0 = gend;
    g++;
  }
}

// ---------- STREAMING gather, CHUNKED: wave owns contiguous node range ----------
__global__ __launch_bounds__(256) void gather_seq_k(
    const float* __restrict__ esrt, const int* __restrict__ off,
    const int* __restrict__ batch, float* __restrict__ hbuf,
    float* __restrict__ gacc, int loff, int store_h) {
  int gid = blockIdx.x * blockDim.x + threadIdx.x;
  int w = gid >> 6, lane = gid & 63;
  const int NW = (gridDim.x * blockDim.x) >> 6;
  const int CHN = (NN + NW - 1) / NW;
  int n0 = w * CHN, n1 = min(n0 + CHN, NN);
  if (n0 >= n1) return;
  const float* base = esrt + lane;
  int cg = batch[n0];
  float gsum = 0.f;
  for (int n = n0; n < n1; n++) {
    int s = off[n], e = off[n + 1];
    float a0 = 0.f, a1 = 0.f, a2 = 0.f, a3 = 0.f;
    float a4 = 0.f, a5 = 0.f, a6 = 0.f, a7 = 0.f;
    int i = s;
    for (; i + 8 <= e; i += 8) {
      a0 += base[(size_t)(i + 0) * 64];
      a1 += base[(size_t)(i + 1) * 64];
      a2 += base[(size_t)(i + 2) * 64];
      a3 += base[(size_t)(i + 3) * 64];
      a4 += base[(size_t)(i + 4) * 64];
      a5 += base[(size_t)(i + 5) * 64];
      a6 += base[(size_t)(i + 6) * 64];
      a7 += base[(size_t)(i + 7) * 64];
    }
    for (; i + 4 <= e; i += 4) {
      a0 += base[(size_t)(i + 0) * 64];
      a1 += base[(size_t)(i + 1) * 64];
      a2 += base[(size_t)(i + 2) * 64];
      a3 += base[(size_t)(i + 3) * 64];
    }
    for (; i < e; i++) a0 += base[(size_t)i * 64];
    float acc = ((a0 + a1) + (a2 + a3)) + ((a4 + a5) + (a6 + a7));
    float hv = acc / (float)max(e - s, 1);
    if (store_h) hbuf[(size_t)n * 64 + lane] = hv;
    int g = batch[n];                   // uniform scalar load
    if (g != cg) {
      atomicAdd(&gacc[cg * 256 + loff + lane], gsum);
      gsum = 0.f;
      cg = g;
    }
    gsum += hv;
  }
  atomicAdd(&gacc[cg * 256 + loff + lane], gsum);
}

// ---------- CSR-ordered edge MLP, MULTI-TILE: grid-stride over 64-edge tiles ----------
// esrt[i] = relu([h[rowsrt[i]],esrt[i]]@W1+b1)@W2+b2 in-place (sequential R/W).
// ge-pool into padded LDS bins (stride 65 -> 16 bins of a column hit 16 distinct
// banks), accumulated across ~12 tiles, ONE flush per block (~1024 global
// atomics/block vs r8's 1024/tile -> 12x fewer; fixes the r8 atomic-flood).
__global__ __launch_bounds__(256) void mlp_csr_k(
    const float* __restrict__ hbuf, float* __restrict__ esrt,
    const int* __restrict__ rowsrt, const int* __restrict__ ebs,
    const u16* __restrict__ W1T, const float* __restrict__ b1,
    const u16* __restrict__ W2T, const float* __restrict__ b2,
    float* __restrict__ gacc, int loff) {
  __shared__ u16 sh[64 * 136];           // 17408B: xin overlays hid
  __shared__ float lacc[NGR * 65];       // padded ge-pool bins (4160B)
  u16* xin = sh;
  u16* hid = sh;
  const int t = threadIdx.x;
  const int lane = t & 63;
  const int wave = t >> 6;
  const int m16 = lane & 15;
  const int quad = lane >> 4;

  for (int i = t; i < NGR * 65; i += 256) lacc[i] = 0.f;

  // ---- preload B fragments + biases (once per block) ----
  bf16x8 B1[2][4], B2[4];
#pragma unroll
  for (int ni = 0; ni < 2; ni++)
#pragma unroll
    for (int ki = 0; ki < 4; ki++)
      B1[ni][ki] = *(const bf16x8*)(W1T + (wave * 32 + ni * 16 + m16) * 128 + ki * 32 + quad * 8);
#pragma unroll
  for (int ki = 0; ki < 4; ki++)
    B2[ki] = *(const bf16x8*)(W2T + (wave * 16 + m16) * 128 + ki * 32 + quad * 8);
  float b1v0 = b1[wave * 32 + m16];
  float b1v1 = b1[wave * 32 + 16 + m16];
  float b2v = b2[wave * 16 + m16];
  const int colo = wave * 16 + m16;
  f32x4 zero = {0.f, 0.f, 0.f, 0.f};

  for (int tile = blockIdx.x; tile < NE / 64; tile += gridDim.x) {
    const int e0 = tile * 64;
    __syncthreads();                     // prev tile's hid reads / lacc init done

    // ---- stage xin[64][128] = [hbuf[rowsrt[i]], esrt[i]] as bf16 ----
#pragma unroll
    for (int it = 0; it < 8; it++) {
      int f = it * 256 + t;
      int r = f >> 5;
      int c = (f & 31) * 4;
      const float* src;
      if (c < 64) {
        src = hbuf + (size_t)rowsrt[e0 + r] * 64 + c;
      } else {
        src = esrt + (size_t)(e0 + r) * 64 + (c - 64);
      }
      float4 v = *(const float4*)src;
      u32 p0 = (u32)f2bf(v.x) | ((u32)f2bf(v.y) << 16);
      u32 p1 = (u32)f2bf(v.z) | ((u32)f2bf(v.w) << 16);
      u32* dst = (u32*)&xin[r * 136 + c];
      dst[0] = p0;
      dst[1] = p1;
    }
    __syncthreads();

    // ---- GEMM1 -> acc1 (regs) ----
    f32x4 acc1[2][4];
#pragma unroll
    for (int ni = 0; ni < 2; ni++)
#pragma unroll
      for (int mi = 0; mi < 4; mi++) acc1[ni][mi] = zero;
#pragma unroll
    for (int ki = 0; ki < 4; ki++) {
#pragma unroll
      for (int mi = 0; mi < 4; mi++) {
        bf16x8 A = *(const bf16x8*)&xin[(mi * 16 + m16) * 136 + ki * 32 + quad * 8];
        acc1[0][mi] = __builtin_amdgcn_mfma_f32_16x16x32_bf16(A, B1[0][ki], acc1[0][mi], 0, 0, 0);
        acc1[1][mi] = __builtin_amdgcn_mfma_f32_16x16x32_bf16(A, B1[1][ki], acc1[1][mi], 0, 0, 0);
      }
    }
    __syncthreads();                     // xin reads done before hid overwrite

#pragma unroll
    for (int mi = 0; mi < 4; mi++) {
#pragma unroll
      for (int reg = 0; reg < 4; reg++) {
        int r = mi * 16 + quad * 4 + reg;
        hid[r * 136 + wave * 32 + m16]      = f2bf(fmaxf(acc1[0][mi][reg] + b1v0, 0.f));
        hid[r * 136 + wave * 32 + 16 + m16] = f2bf(fmaxf(acc1[1][mi][reg] + b1v1, 0.f));
      }
    }
    __syncthreads();

    // ---- GEMM2 -> acc2 ----
    f32x4 acc2[4];
#pragma unroll
    for (int mi = 0; mi < 4; mi++) acc2[mi] = zero;
#pragma unroll
    for (int ki = 0; ki < 4; ki++) {
#pragma unroll
      for (int mi = 0; mi < 4; mi++) {
        bf16x8 A = *(const bf16x8*)&hid[(mi * 16 + m16) * 136 + ki * 32 + quad * 8];
        acc2[mi] = __builtin_amdgcn_mfma_f32_16x16x32_bf16(A, B2[ki], acc2[mi], 0, 0, 0);
      }
    }

    // ---- in-place esrt write + padded LDS ge-pool binning ----
#pragma unroll
    for (int mi = 0; mi < 4; mi++) {
#pragma unroll
      for (int reg = 0; reg < 4; reg++) {
        int r = mi * 16 + quad * 4 + reg;
        float v = acc2[mi][reg] + b2v;
        esrt[(size_t)(e0 + r) * 64 + colo] = v;
        atomicAdd(&lacc[ebs[e0 + r] * 65 + colo], v);
      }
    }
  }

  // ---- ONE flush per block ----
  __syncthreads();
#pragma unroll
  for (int i = 0; i < 4; i++) {
    int idx = t + 256 * i;               // g = idx>>6, col = idx&63
    float v = lacc[(idx >> 6) * 65 + (idx & 63)];
    if (v != 0.f) atomicAdd(&gacc[(idx >> 6) * 256 + loff + (idx & 63)], v);
  }
}

// ---------- FALLBACK kernels (round-2 proven path, used only if ws too small) ----------
__global__ __launch_bounds__(256) void gather_k(
    const float* __restrict__ ea, const int* __restrict__ off,
    const int* __restrict__ eid, const int* __restrict__ batch,
    float* __restrict__ hbuf, float* __restrict__ gacc,
    int loff, int store_h) {
  int gid = blockIdx.x * blockDim.x + threadIdx.x;
  int w = gid >> 6, lane = gid & 63;
  int nw = (gridDim.x * blockDim.x) >> 6;
  const float* base = ea + lane;
  for (int n = w; n < NN; n += nw) {
    int s = off[n], e = off[n + 1];
    int g = batch[n];
    float a0 = 0.f, a1 = 0.f, a2 = 0.f, a3 = 0.f;
    int i = s;
    for (; i + 4 <= e; i += 4) {
      int e0 = eid[i], e1 = eid[i + 1], e2 = eid[i + 2], e3 = eid[i + 3];
      a0 += base[(size_t)e0 * 64];
      a1 += base[(size_t)e1 * 64];
      a2 += base[(size_t)e2 * 64];
      a3 += base[(size_t)e3 * 64];
    }
    for (; i < e; i++) a0 += base[(size_t)eid[i] * 64];
    float acc = (a0 + a1) + (a2 + a3);
    float hv = acc / (float)max(e - s, 1);
    if (store_h) hbuf[(size_t)n * 64 + lane] = hv;
    atomicAdd(&gacc[g * 256 + loff + lane], hv);
  }
}

__global__ __launch_bounds__(256) void pool_seg_k(const float* __restrict__ ea,
                                                  const int* __restrict__ eoff,
                                                  float* __restrict__ gacc, int loff) {
  int gid = blockIdx.x * blockDim.x + threadIdx.x;
  int w = gid >> 6, lane = gid & 63;
  const int NW = (gridDim.x * blockDim.x) >> 6;
  const int CH = (NE + NW - 1) / NW;
  int r0 = w * CH, r1 = min(r0 + CH, NE);
  if (r0 >= r1) return;
  int g = 0;
  while (eoff[g + 1] <= r0) g++;
  const float* base = ea + lane;
  while (r0 < r1) {
    int gend = min(r1, eoff[g + 1]);
    float a0 = 0.f, a1 = 0.f, a2 = 0.f, a3 = 0.f;
    float a4 = 0.f, a5 = 0.f, a6 = 0.f, a7 = 0.f;
    int r = r0;
    for (; r + 8 <= gend; r += 8) {
      a0 += base[(size_t)(r + 0) * 64];
      a1 += base[(size_t)(r + 1) * 64];
      a2 += base[(size_t)(r + 2) * 64];
      a3 += base[(size_t)(r + 3) * 64];
      a4 += base[(size_t)(r + 4) * 64];
      a5 += base[(size_t)(r + 5) * 64];
      a6 += base[(size_t)(r + 6) * 64];
      a7 += base[(size_t)(r + 7) * 64];
    }
    for (; r < gend; r++) a0 += base[(size_t)r * 64];
    float s = ((a0 + a1) + (a2 + a3)) + ((a4 + a5) + (a6 + a7));
    atomicAdd(&gacc[g * 256 + loff + lane], s);
    r0 = gend;
    g++;
  }
}

__global__ __launch_bounds__(256) void mlp_fallback_k(
    const float* hbuf, float* ea, const int* rowp,
    const u16* W1T, const float* b1,
    const u16* W2T, const float* b2,
    const int* ebatch, float* gacc, int loff) {
  __shared__ u16 sh[2 * 64 * 136];
  u16* xin = sh;
  u16* hid = sh + 64 * 136;
  const int t = threadIdx.x;
  const int e0 = blockIdx.x * 64;
  const int lane = t & 63;
  const int wave = t >> 6;
  const int m16 = lane & 15;
  const int quad = lane >> 4;

  bf16x8 B1[2][4], B2[4];
#pragma unroll
  for (int ni = 0; ni < 2; ni++)
#pragma unroll
    for (int ki = 0; ki < 4; ki++)
      B1[ni][ki] = *(const bf16x8*)(W1T + (wave * 32 + ni * 16 + m16) * 128 + ki * 32 + quad * 8);
#pragma unroll
  for (int ki = 0; ki < 4; ki++)
    B2[ki] = *(const bf16x8*)(W2T + (wave * 16 + m16) * 128 + ki * 32 + quad * 8);

#pragma unroll
  for (int it = 0; it < 8; it++) {
    int f = it * 256 + t;
    int r = f >> 5;
    int c = (f & 31) * 4;
    const float* src;
    if (c < 64) {
      int nd = rowp[e0 + r];
      src = hbuf + (size_t)nd * 64 + c;
    } else {
      src = ea + (size_t)(e0 + r) * 64 + (c - 64);
    }
    float4 v = *(const float4*)src;
    u32 p0 = (u32)f2bf(v.x) | ((u32)f2bf(v.y) << 16);
    u32 p1 = (u32)f2bf(v.z) | ((u32)f2bf(v.w) << 16);
    u32* dst = (u32*)&xin[r * 136 + c];
    dst[0] = p0;
    dst[1] = p1;
  }
  __syncthreads();

  f32x4 zero = {0.f, 0.f, 0.f, 0.f};
  f32x4 acc1[2][4];
#pragma unroll
  for (int ni = 0; ni < 2; ni++)
#pragma unroll
    for (int mi = 0; mi < 4; mi++) acc1[ni][mi] = zero;
#pragma unroll
  for (int ki = 0; ki < 4; ki++) {
#pragma unroll
    for (int mi = 0; mi < 4; mi++) {
      bf16x8 A = *(const bf16x8*)&xin[(mi * 16 + m16) * 136 + ki * 32 + quad * 8];
      acc1[0][mi] = __builtin_amdgcn_mfma_f32_16x16x32_bf16(A, B1[0][ki], acc1[0][mi], 0, 0, 0);
      acc1[1][mi] = __builtin_amdgcn_mfma_f32_16x16x32_bf16(A, B1[1][ki], acc1[1][mi], 0, 0, 0);
    }
  }
  float b1v0 = b1[wave * 32 + m16];
  float b1v1 = b1[wave * 32 + 16 + m16];
#pragma unroll
  for (int mi = 0; mi < 4; mi++) {
#pragma unroll
    for (int reg = 0; reg < 4; reg++) {
      int r = mi * 16 + quad * 4 + reg;
      hid[r * 136 + wave * 32 + m16]      = f2bf(fmaxf(acc1[0][mi][reg] + b1v0, 0.f));
      hid[r * 136 + wave * 32 + 16 + m16] = f2bf(fmaxf(acc1[1][mi][reg] + b1v1, 0.f));
    }
  }
  __syncthreads();

  f32x4 acc2[4];
#pragma unroll
  for (int mi = 0; mi < 4; mi++) acc2[mi] = zero;
#pragma unroll
  for (int ki = 0; ki < 4; ki++) {
#pragma unroll
    for (int mi = 0; mi < 4; mi++) {
      bf16x8 A = *(const bf16x8*)&hid[(mi * 16 + m16) * 136 + ki * 32 + quad * 8];
      acc2[mi] = __builtin_amdgcn_mfma_f32_16x16x32_bf16(A, B2[ki], acc2[mi], 0, 0, 0);
    }
  }
  float b2v = b2[wave * 16 + m16];
#pragma unroll
  for (int mi = 0; mi < 4; mi++) {
#pragma unroll
    for (int reg = 0; reg < 4; reg++) {
      int r = mi * 16 + quad * 4 + reg;
      ea[(size_t)(e0 + r) * 64 + wave * 16 + m16] = acc2[mi][reg] + b2v;
    }
  }
  int g0 = ebatch[e0], g1 = ebatch[e0 + 63];
  int colo = wave * 16 + m16;
  if (g0 == g1) {
    float s = 0.f;
#pragma unroll
    for (int mi = 0; mi < 4; mi++)
#pragma unroll
      for (int reg = 0; reg < 4; reg++) s += acc2[mi][reg] + b2v;
    s += __shfl_xor(s, 16);
    s += __shfl_xor(s, 32);
    if (quad == 0) atomicAdd(&gacc[g0 * 256 + loff + colo], s);
  } else {
#pragma unroll
    for (int mi = 0; mi < 4; mi++)
#pragma unroll
      for (int reg = 0; reg < 4; reg++) {
        int r = mi * 16 + quad * 4 + reg;
        atomicAdd(&gacc[ebatch[e0 + r] * 256 + loff + colo], acc2[mi][reg] + b2v);
      }
  }
}

// ---------- finalize: means (acc already in output layout), head, f32 out ----------
__global__ __launch_bounds__(256) void finalize_k(
    const float* gn_acc, const float* ge_acc,
    const int* cnt_n, const int* cnt_e,
    const float* Wo1, const float* bo1,
    const float* Wo2, const float* bo2,
    const float* Wo3, const float* bo3,
    float* out) {
  __shared__ float attr[16][512];
  __shared__ float o1[16][128];
  __shared__ float o2[16][128];
  int t = threadIdx.x;
  for (int i = t; i < 4096; i += 256) {
    int g = i >> 8, c = i & 255;
    float vn = gn_acc[i] / (float)max(cnt_n[g], 1);
    float ve = ge_acc[i] / (float)max(cnt_e[g], 1);
    out[i] = vn;
    out[4096 + i] = ve;
    attr[g][c] = vn;
    attr[g][256 + c] = ve;
  }
  __syncthreads();
  {
    int j = t & 127, gh = t >> 7;
    float a[8];
#pragma unroll
    for (int q = 0; q < 8; q++) a[q] = bo1[j];
    for (int k = 0; k < 512; k++) {
      float w = Wo1[k * 128 + j];
#pragma unroll
      for (int q = 0; q < 8; q++) a[q] = fmaf(attr[gh * 8 + q][k], w, a[q]);
    }
#pragma unroll
    for (int q = 0; q < 8; q++) o1[gh * 8 + q][j] = fmaxf(a[q], 0.f);
  }
  __syncthreads();
  {
    int j = t & 127, gh = t >> 7;
    float a[8];
#pragma unroll
    for (int q = 0; q < 8; q++) a[q] = bo2[j];
    for (int k = 0; k < 128; k++) {
      float w = Wo2[k * 128 + j];
#pragma unroll
      for (int q = 0; q < 8; q++) a[q] = fmaf(o1[gh * 8 + q][k], w, a[q]);
    }
#pragma unroll
    for (int q = 0; q < 8; q++) o2[gh * 8 + q][j] = fmaxf(a[q], 0.f);
  }
  __syncthreads();
  {
    int j = t & 31, gb = t >> 5;
#pragma unroll
    for (int q = 0; q < 2; q++) {
      int g = gb * 2 + q;
      float a = bo3[j];
      for (int k = 0; k < 128; k++) a = fmaf(o2[g][k], Wo3[k * 32 + j], a);
      out[8192 + g * 32 + j] = a;
    }
  }
}

extern "C" void kernel_launch(void* const* d_in, const int* in_sizes, int n_in,
                              void* d_out, int out_size, void* d_ws, size_t ws_size,
                              hipStream_t stream) {
  float* ea = (float*)d_in[1];               // [NE,64] f32
  const int* edge_index = (const int*)d_in[3];
  const int* row = edge_index;
  const int* col = edge_index + NE;
  const int* batch = (const int*)d_in[4];
  const int* ebatch = (const int*)d_in[5];
  const float* W1s = (const float*)d_in[6];  // [3,128,128]
  const float* b1s = (const float*)d_in[7];  // [3,128]
  const float* W2s = (const float*)d_in[8];  // [3,128,64]
  const float* b2s = (const float*)d_in[9];  // [3,64]
  const float* Wo1 = (const float*)d_in[10];
  const float* bo1 = (const float*)d_in[11];
  const float* Wo2 = (const float*)d_in[12];
  const float* bo2 = (const float*)d_in[13];
  const float* Wo3 = (const float*)d_in[14];
  const float* bo3 = (const float*)d_in[15];

  char* p = (char*)d_ws;
  auto alloc = [&](size_t b) { char* r = p; p += (b + 255) & ~(size_t)255; return r; };
  // ---- zero region (one memset) ----
  int* deg = (int*)alloc(NN * 4);
  int* cursor = (int*)alloc(NN * 4);
  int* cnt_n = (int*)alloc(64);
  int* cnt_e = (int*)alloc(64);
  float* gn_acc = (float*)alloc(NGR * 256 * 4);
  float* ge_acc = (float*)alloc(NGR * 256 * 4);
  size_t zbytes = (size_t)(p - (char*)d_ws);
  // ---- non-zeroed ----
  int* csr_off = (int*)alloc((NN + 1) * 4);
  int* csr_eid = (int*)alloc((size_t)NE * 4);
  int* pos = (int*)alloc((size_t)NE * 4);
  int* rowsrt = (int*)alloc((size_t)NE * 4);
  int* ebs = (int*)alloc((size_t)NE * 4);
  float* hbuf = (float*)alloc((size_t)NN * 64 * 4);
  u16* W1T = (u16*)alloc(3 * 128 * 128 * 2);
  u16* W2T = (u16*)alloc(3 * 64 * 128 * 2);
  int* eoff = (int*)alloc((NGR + 1) * 4);
  // esrt: CSR-permuted edge rows (205MB) — only if workspace allows
  float* esrt = nullptr;
  {
    size_t used = (size_t)(p - (char*)d_ws);
    size_t need = (size_t)NE * 64 * 4 + 512;
    if (ws_size >= used + need) esrt = (float*)alloc((size_t)NE * 64 * 4);
  }

  hipMemsetAsync(d_ws, 0, zbytes, stream);

  prep_w_k<<<(3 * 128 * 128 + 3 * 128 * 64 + 255) / 256, 256, 0, stream>>>(W1s, W2s, W1T, W2T);
  hist_deg<<<(NE + 255) / 256, 256, 0, stream>>>(col, deg);
  count_graphs<<<1, 64, 0, stream>>>(batch, ebatch, cnt_n, cnt_e, eoff);
  scan_deg<<<1, 256, 0, stream>>>(deg, csr_off);
  fill_csr<<<(NE + 255) / 256, 256, 0, stream>>>(col, row, ebatch, csr_off, cursor,
                                                 csr_eid, pos, rowsrt, ebs);

  if (esrt) {
    // ---- CSR-native path: permute once; everything else is sequential ----
    pool_perm_k<<<2048, 256, 0, stream>>>(ea, eoff, pos, esrt, ge_acc, 0);
    gather_seq_k<<<2048, 256, 0, stream>>>(esrt, csr_off, batch, hbuf, gn_acc, 0, 1);
    for (int l = 0; l < 3; l++) {
      mlp_csr_k<<<1024, 256, 0, stream>>>(hbuf, esrt, rowsrt, ebs,
          W1T + l * 16384, b1s + l * 128, W2T + l * 8192, b2s + l * 64,
          ge_acc, (l + 1) * 64);
      gather_seq_k<<<2048, 256, 0, stream>>>(esrt, csr_off, batch, hbuf,
                                             gn_acc, (l + 1) * 64, l < 2 ? 1 : 0);
    }
  } else {
    // ---- fallback (round-2 proven): random gather via uniform eid ----
    pool_seg_k<<<2048, 256, 0, stream>>>(ea, eoff, ge_acc, 0);
    gather_k<<<2048, 256, 0, stream>>>(ea, csr_off, csr_eid, batch, hbuf, gn_acc, 0, 1);
    for (int l = 0; l < 3; l++) {
      mlp_fallback_k<<<NE / 64, 256, 0, stream>>>(hbuf, ea, row,
          W1T + l * 16384, b1s + l * 128, W2T + l * 8192, b2s + l * 64,
          ebatch, ge_acc, (l + 1) * 64);
      gather_k<<<2048, 256, 0, stream>>>(ea, csr_off, csr_eid, batch, hbuf,
                                         gn_acc, (l + 1) * 64, l < 2 ? 1 : 0);
    }
  }

  finalize_k<<<1, 256, 0, stream>>>(gn_acc, ge_acc, cnt_n, cnt_e,
      Wo1, bo1, Wo2, bo2, Wo3, bo3, (float*)d_out);
}

// Round 10
// 1881.652 us; speedup vs baseline: 1.4308x; 1.0293x over previous
//
#include <hip/hip_runtime.h>

#define NN 50000      // nodes
#define NE 800000     // edges
#define NGR 16        // graphs

typedef unsigned short u16;
typedef unsigned int u32;
typedef __attribute__((ext_vector_type(8))) short bf16x8;
typedef __attribute__((ext_vector_type(4))) float f32x4;

__device__ __forceinline__ u16 f2bf(float f) {       // RNE f32->bf16
  u32 u = __float_as_uint(f);
  return (u16)((u + 0x7fffu + ((u >> 16) & 1u)) >> 16);
}
__device__ __forceinline__ float bflo(u32 v) { return __uint_as_float(v << 16); }
__device__ __forceinline__ float bfhi(u32 v) { return __uint_as_float(v & 0xffff0000u); }

// ---------- degree histogram ----------
__global__ void hist_deg(const int* col, int* deg) {
  int e = blockIdx.x * blockDim.x + threadIdx.x;
  if (e < NE) atomicAdd(&deg[col[e]], 1);
}

// ---------- per-graph counts (sorted ids) + edge segment offsets ----------
__device__ int lbound(const int* a, int n, int v) {
  int lo = 0, hi = n;
  while (lo < hi) { int m = (lo + hi) >> 1; if (a[m] < v) lo = m + 1; else hi = m; }
  return lo;
}
__global__ void count_graphs(const int* batch, const int* ebatch, int* cnt_n, int* cnt_e,
                             int* eoff) {
  int t = threadIdx.x;
  if (t < NGR) cnt_n[t] = lbound(batch, NN, t + 1) - lbound(batch, NN, t);
  else if (t < 2 * NGR) { int g = t - NGR; cnt_e[g] = lbound(ebatch, NE, g + 1) - lbound(ebatch, NE, g); }
  else if (t < 3 * NGR + 1) { int g = t - 2 * NGR; eoff[g] = lbound(ebatch, NE, g); }  // eoff[16]=NE
}

// ---------- exclusive scan of deg -> csr_off (single block) ----------
__global__ __launch_bounds__(256) void scan_deg(const int* deg, int* off) {
  __shared__ int sums[256];
  const int CH = (NN + 255) / 256;
  int t = threadIdx.x;
  int base = t * CH;
  int s = 0;
  for (int i = 0; i < CH; i++) { int idx = base + i; if (idx < NN) s += deg[idx]; }
  sums[t] = s;
  __syncthreads();
  for (int d = 1; d < 256; d <<= 1) {
    int v = (t >= d) ? sums[t - d] : 0;
    __syncthreads();
    sums[t] += v;
    __syncthreads();
  }
  int run = (t == 0) ? 0 : sums[t - 1];
  for (int i = 0; i < CH; i++) { int idx = base + i; if (idx < NN) { off[idx] = run; run += deg[idx]; } }
  if (t == 255) off[NN] = run;
}

// ---------- CSR fill: eid, pos, and CSR-ordered row/graph tables ----------
__global__ void fill_csr(const int* col, const int* rowp, const int* ebatch,
                         const int* off, int* cursor, int* eid, int* pos,
                         int* rowsrt, int* ebs) {
  int e = blockIdx.x * blockDim.x + threadIdx.x;
  if (e < NE) {
    int c = col[e];
    int p = atomicAdd(&cursor[c], 1);
    int slot = off[c] + p;
    eid[slot] = e;
    pos[e] = slot;
    rowsrt[slot] = rowp[e];
    ebs[slot] = ebatch[e];
  }
}

// ---------- weights f32 -> bf16 TRANSPOSED (W1T[l][n][k], W2T[l][n][k]) ----------
__global__ void prep_w_k(const float* W1, const float* W2, u16* W1T, u16* W2T) {
  int i = blockIdx.x * 256 + threadIdx.x;
  if (i < 3 * 128 * 128) {
    int l = i / 16384, k = (i >> 7) & 127, n = i & 127;
    W1T[l * 16384 + n * 128 + k] = f2bf(W1[i]);
  } else {
    int j = i - 3 * 128 * 128;
    if (j < 3 * 128 * 64) {
      int l = j / 8192, k = (j >> 6) & 127, n = j & 63;
      W2T[l * 8192 + n * 128 + k] = f2bf(W2[j]);
    }
  }
}

// ---------- layer-0: segmented ge pool (f32) + CSR permute -> esrt BF16 ----------
__global__ __launch_bounds__(256) void pool_perm_k(const float* __restrict__ ea,
                                                   const int* __restrict__ eoff,
                                                   const int* __restrict__ pos,
                                                   u16* __restrict__ esrt,
                                                   float* __restrict__ gacc, int loff) {
  int gid = blockIdx.x * blockDim.x + threadIdx.x;
  int w = gid >> 6, lane = gid & 63;
  const int NW = (gridDim.x * blockDim.x) >> 6;
  const int CH = (NE + NW - 1) / NW;
  int r0 = w * CH, r1 = min(r0 + CH, NE);
  if (r0 >= r1) return;
  int g = 0;
  while (eoff[g + 1] <= r0) g++;       // <=16 scalar iters, once per wave
  const float* base = ea + lane;
  u16* sbase = esrt + lane;
  while (r0 < r1) {
    int gend = min(r1, eoff[g + 1]);
    float a0 = 0.f, a1 = 0.f, a2 = 0.f, a3 = 0.f;
    float a4 = 0.f, a5 = 0.f, a6 = 0.f, a7 = 0.f;
    int r = r0;
    for (; r + 8 <= gend; r += 8) {
      float v0 = base[(size_t)(r + 0) * 64];
      float v1 = base[(size_t)(r + 1) * 64];
      float v2 = base[(size_t)(r + 2) * 64];
      float v3 = base[(size_t)(r + 3) * 64];
      float v4 = base[(size_t)(r + 4) * 64];
      float v5 = base[(size_t)(r + 5) * 64];
      float v6 = base[(size_t)(r + 6) * 64];
      float v7 = base[(size_t)(r + 7) * 64];
      sbase[(size_t)pos[r + 0] * 64] = f2bf(v0);
      sbase[(size_t)pos[r + 1] * 64] = f2bf(v1);
      sbase[(size_t)pos[r + 2] * 64] = f2bf(v2);
      sbase[(size_t)pos[r + 3] * 64] = f2bf(v3);
      sbase[(size_t)pos[r + 4] * 64] = f2bf(v4);
      sbase[(size_t)pos[r + 5] * 64] = f2bf(v5);
      sbase[(size_t)pos[r + 6] * 64] = f2bf(v6);
      sbase[(size_t)pos[r + 7] * 64] = f2bf(v7);
      a0 += v0; a1 += v1; a2 += v2; a3 += v3;
      a4 += v4; a5 += v5; a6 += v6; a7 += v7;
    }
    for (; r < gend; r++) {
      float v = base[(size_t)r * 64];
      sbase[(size_t)pos[r] * 64] = f2bf(v);
      a0 += v;
    }
    float s = ((a0 + a1) + (a2 + a3)) + ((a4 + a5) + (a6 + a7));
    atomicAdd(&gacc[g * 256 + loff + lane], s);
    r0 = gend;
    g++;
  }
}

// ---------- STREAMING gather (bf16): lane = col-pair, half-wave = row slot ----------
// One u32 load = 2 bf16 cols; wave-load covers 2 rows x 128B = 256B sequential.
// Chunked contiguous node range per wave; per-graph register pooling.
__global__ __launch_bounds__(256) void gather_seq_k(
    const u16* __restrict__ esrt, const int* __restrict__ off,
    const int* __restrict__ batch, u16* __restrict__ hbuf,
    float* __restrict__ gacc, int loff, int store_h) {
  int gid = blockIdx.x * blockDim.x + threadIdx.x;
  int w = gid >> 6, lane = gid & 63;
  const int NW = (gridDim.x * blockDim.x) >> 6;
  const int CHN = (NN + NW - 1) / NW;
  int n0 = w * CHN, n1 = min(n0 + CHN, NN);
  if (n0 >= n1) return;
  int h = lane >> 5, c2 = lane & 31;       // col pair (2*c2, 2*c2+1)
  const u32* base = (const u32*)esrt + c2; // row stride = 32 u32
  int cg = batch[n0];
  float gsx = 0.f, gsy = 0.f;
  for (int n = n0; n < n1; n++) {
    int s = off[n], e = off[n + 1];
    float x0 = 0.f, y0 = 0.f, x1 = 0.f, y1 = 0.f;
    float x2 = 0.f, y2 = 0.f, x3 = 0.f, y3 = 0.f;
    int i = s;
    for (; i + 8 <= e; i += 8) {           // 8 rows/iter, this half loads 4
      u32 v0 = base[(size_t)(i + 0 + h) * 32];
      u32 v1 = base[(size_t)(i + 2 + h) * 32];
      u32 v2 = base[(size_t)(i + 4 + h) * 32];
      u32 v3 = base[(size_t)(i + 6 + h) * 32];
      x0 += bflo(v0); y0 += bfhi(v0);
      x1 += bflo(v1); y1 += bfhi(v1);
      x2 += bflo(v2); y2 += bfhi(v2);
      x3 += bflo(v3); y3 += bfhi(v3);
    }
    for (; i + 2 <= e; i += 2) {
      u32 v = base[(size_t)(i + h) * 32];
      x0 += bflo(v); y0 += bfhi(v);
    }
    if (i < e && h == 0) {
      u32 v = base[(size_t)i * 32];
      x0 += bflo(v); y0 += bfhi(v);
    }
    float sx = (x0 + x1) + (x2 + x3);
    float sy = (y0 + y1) + (y2 + y3);
    sx += __shfl_xor(sx, 32);
    sy += __shfl_xor(sy, 32);
    if (h == 0) {
      float inv = 1.f / (float)max(e - s, 1);
      float hx = sx * inv, hy = sy * inv;
      if (store_h)
        ((u32*)hbuf)[(size_t)n * 32 + c2] = (u32)f2bf(hx) | ((u32)f2bf(hy) << 16);
      int g = batch[n];                    // uniform scalar load
      if (g != cg) {
        float* dst = gacc + cg * 256 + loff + c2 * 2;
        atomicAdd(dst + 0, gsx);
        atomicAdd(dst + 1, gsy);
        gsx = 0.f; gsy = 0.f;
        cg = g;
      }
      gsx += hx; gsy += hy;
    }
  }
  if (h == 0) {
    float* dst = gacc + cg * 256 + loff + c2 * 2;
    atomicAdd(dst + 0, gsx);
    atomicAdd(dst + 1, gsy);
  }
}

// ---------- CSR-ordered edge MLP (bf16 esrt/hbuf), MULTI-TILE grid-stride ----------
// Staging = pure 16B->16B copies (no cvt). In-place bf16 esrt write. ge-pool
// bins f32 pre-rounding values (accuracy preserved); one flush per block.
__global__ __launch_bounds__(256) void mlp_csr_k(
    const u16* __restrict__ hbuf, u16* __restrict__ esrt,
    const int* __restrict__ rowsrt, const int* __restrict__ ebs,
    const u16* __restrict__ W1T, const float* __restrict__ b1,
    const u16* __restrict__ W2T, const float* __restrict__ b2,
    float* __restrict__ gacc, int loff) {
  __shared__ u16 sh[64 * 136];           // 17408B: xin overlays hid
  __shared__ float lacc[NGR * 65];       // padded ge-pool bins
  u16* xin = sh;
  u16* hid = sh;
  const int t = threadIdx.x;
  const int lane = t & 63;
  const int wave = t >> 6;
  const int m16 = lane & 15;
  const int quad = lane >> 4;

  for (int i = t; i < NGR * 65; i += 256) lacc[i] = 0.f;

  // ---- preload B fragments + biases (once per block) ----
  bf16x8 B1[2][4], B2[4];
#pragma unroll
  for (int ni = 0; ni < 2; ni++)
#pragma unroll
    for (int ki = 0; ki < 4; ki++)
      B1[ni][ki] = *(const bf16x8*)(W1T + (wave * 32 + ni * 16 + m16) * 128 + ki * 32 + quad * 8);
#pragma unroll
  for (int ki = 0; ki < 4; ki++)
    B2[ki] = *(const bf16x8*)(W2T + (wave * 16 + m16) * 128 + ki * 32 + quad * 8);
  float b1v0 = b1[wave * 32 + m16];
  float b1v1 = b1[wave * 32 + 16 + m16];
  float b2v = b2[wave * 16 + m16];
  const int colo = wave * 16 + m16;
  f32x4 zero = {0.f, 0.f, 0.f, 0.f};

  for (int tile = blockIdx.x; tile < NE / 64; tile += gridDim.x) {
    const int e0 = tile * 64;
    __syncthreads();                     // prev tile's hid reads done

    // ---- stage xin[64][128] bf16 = [hbuf[rowsrt[i]], esrt[i]] : 4x 16B copies ----
#pragma unroll
    for (int it = 0; it < 4; it++) {
      int f = it * 256 + t;              // 16B-chunk id 0..1023
      int r = f >> 4;                    // row 0..63
      int c8 = (f & 15) * 8;             // col base 0..120 (thread-invariant)
      const u16* src;
      if (c8 < 64) {
        src = hbuf + (size_t)rowsrt[e0 + r] * 64 + c8;
      } else {
        src = esrt + (size_t)(e0 + r) * 64 + (c8 - 64);
      }
      *(bf16x8*)&xin[r * 136 + c8] = *(const bf16x8*)src;
    }
    __syncthreads();

    // ---- GEMM1 -> acc1 (regs) ----
    f32x4 acc1[2][4];
#pragma unroll
    for (int ni = 0; ni < 2; ni++)
#pragma unroll
      for (int mi = 0; mi < 4; mi++) acc1[ni][mi] = zero;
#pragma unroll
    for (int ki = 0; ki < 4; ki++) {
#pragma unroll
      for (int mi = 0; mi < 4; mi++) {
        bf16x8 A = *(const bf16x8*)&xin[(mi * 16 + m16) * 136 + ki * 32 + quad * 8];
        acc1[0][mi] = __builtin_amdgcn_mfma_f32_16x16x32_bf16(A, B1[0][ki], acc1[0][mi], 0, 0, 0);
        acc1[1][mi] = __builtin_amdgcn_mfma_f32_16x16x32_bf16(A, B1[1][ki], acc1[1][mi], 0, 0, 0);
      }
    }
    __syncthreads();                     // xin reads done before hid overwrite

#pragma unroll
    for (int mi = 0; mi < 4; mi++) {
#pragma unroll
      for (int reg = 0; reg < 4; reg++) {
        int r = mi * 16 + quad * 4 + reg;
        hid[r * 136 + wave * 32 + m16]      = f2bf(fmaxf(acc1[0][mi][reg] + b1v0, 0.f));
        hid[r * 136 + wave * 32 + 16 + m16] = f2bf(fmaxf(acc1[1][mi][reg] + b1v1, 0.f));
      }
    }
    __syncthreads();

    // ---- GEMM2 -> acc2 ----
    f32x4 acc2[4];
#pragma unroll
    for (int mi = 0; mi < 4; mi++) acc2[mi] = zero;
#pragma unroll
    for (int ki = 0; ki < 4; ki++) {
#pragma unroll
      for (int mi = 0; mi < 4; mi++) {
        bf16x8 A = *(const bf16x8*)&hid[(mi * 16 + m16) * 136 + ki * 32 + quad * 8];
        acc2[mi] = __builtin_amdgcn_mfma_f32_16x16x32_bf16(A, B2[ki], acc2[mi], 0, 0, 0);
      }
    }

    // ---- in-place bf16 esrt write + padded LDS ge-pool binning (f32) ----
#pragma unroll
    for (int mi = 0; mi < 4; mi++) {
#pragma unroll
      for (int reg = 0; reg < 4; reg++) {
        int r = mi * 16 + quad * 4 + reg;
        float v = acc2[mi][reg] + b2v;
        esrt[(size_t)(e0 + r) * 64 + colo] = f2bf(v);
        atomicAdd(&lacc[ebs[e0 + r] * 65 + colo], v);
      }
    }
  }

  // ---- ONE flush per block ----
  __syncthreads();
#pragma unroll
  for (int i = 0; i < 4; i++) {
    int idx = t + 256 * i;               // g = idx>>6, col = idx&63
    float v = lacc[(idx >> 6) * 65 + (idx & 63)];
    if (v != 0.f) atomicAdd(&gacc[(idx >> 6) * 256 + loff + (idx & 63)], v);
  }
}

// ---------- FALLBACK kernels (round-2 proven f32 path, used only if ws too small) ----------
__global__ __launch_bounds__(256) void gather_k(
    const float* __restrict__ ea, const int* __restrict__ off,
    const int* __restrict__ eid, const int* __restrict__ batch,
    float* __restrict__ hbuf, float* __restrict__ gacc,
    int loff, int store_h) {
  int gid = blockIdx.x * blockDim.x + threadIdx.x;
  int w = gid >> 6, lane = gid & 63;
  int nw = (gridDim.x * blockDim.x) >> 6;
  const float* base = ea + lane;
  for (int n = w; n < NN; n += nw) {
    int s = off[n], e = off[n + 1];
    int g = batch[n];
    float a0 = 0.f, a1 = 0.f, a2 = 0.f, a3 = 0.f;
    int i = s;
    for (; i + 4 <= e; i += 4) {
      int e0 = eid[i], e1 = eid[i + 1], e2 = eid[i + 2], e3 = eid[i + 3];
      a0 += base[(size_t)e0 * 64];
      a1 += base[(size_t)e1 * 64];
      a2 += base[(size_t)e2 * 64];
      a3 += base[(size_t)e3 * 64];
    }
    for (; i < e; i++) a0 += base[(size_t)eid[i] * 64];
    float acc = (a0 + a1) + (a2 + a3);
    float hv = acc / (float)max(e - s, 1);
    if (store_h) hbuf[(size_t)n * 64 + lane] = hv;
    atomicAdd(&gacc[g * 256 + loff + lane], hv);
  }
}

__global__ __launch_bounds__(256) void pool_seg_k(const float* __restrict__ ea,
                                                  const int* __restrict__ eoff,
                                                  float* __restrict__ gacc, int loff) {
  int gid = blockIdx.x * blockDim.x + threadIdx.x;
  int w = gid >> 6, lane = gid & 63;
  const int NW = (gridDim.x * blockDim.x) >> 6;
  const int CH = (NE + NW - 1) / NW;
  int r0 = w * CH, r1 = min(r0 + CH, NE);
  if (r0 >= r1) return;
  int g = 0;
  while (eoff[g + 1] <= r0) g++;
  const float* base = ea + lane;
  while (r0 < r1) {
    int gend = min(r1, eoff[g + 1]);
    float a0 = 0.f, a1 = 0.f, a2 = 0.f, a3 = 0.f;
    float a4 = 0.f, a5 = 0.f, a6 = 0.f, a7 = 0.f;
    int r = r0;
    for (; r + 8 <= gend; r += 8) {
      a0 += base[(size_t)(r + 0) * 64];
      a1 += base[(size_t)(r + 1) * 64];
      a2 += base[(size_t)(r + 2) * 64];
      a3 += base[(size_t)(r + 3) * 64];
      a4 += base[(size_t)(r + 4) * 64];
      a5 += base[(size_t)(r + 5) * 64];
      a6 += base[(size_t)(r + 6) * 64];
      a7 += base[(size_t)(r + 7) * 64];
    }
    for (; r < gend; r++) a0 += base[(size_t)r * 64];
    float s = ((a0 + a1) + (a2 + a3)) + ((a4 + a5) + (a6 + a7));
    atomicAdd(&gacc[g * 256 + loff + lane], s);
    r0 = gend;
    g++;
  }
}

__global__ __launch_bounds__(256) void mlp_fallback_k(
    const float* hbuf, float* ea, const int* rowp,
    const u16* W1T, const float* b1,
    const u16* W2T, const float* b2,
    const int* ebatch, float* gacc, int loff) {
  __shared__ u16 sh[2 * 64 * 136];
  u16* xin = sh;
  u16* hid = sh + 64 * 136;
  const int t = threadIdx.x;
  const int e0 = blockIdx.x * 64;
  const int lane = t & 63;
  const int wave = t >> 6;
  const int m16 = lane & 15;
  const int quad = lane >> 4;

  bf16x8 B1[2][4], B2[4];
#pragma unroll
  for (int ni = 0; ni < 2; ni++)
#pragma unroll
    for (int ki = 0; ki < 4; ki++)
      B1[ni][ki] = *(const bf16x8*)(W1T + (wave * 32 + ni * 16 + m16) * 128 + ki * 32 + quad * 8);
#pragma unroll
  for (int ki = 0; ki < 4; ki++)
    B2[ki] = *(const bf16x8*)(W2T + (wave * 16 + m16) * 128 + ki * 32 + quad * 8);

#pragma unroll
  for (int it = 0; it < 8; it++) {
    int f = it * 256 + t;
    int r = f >> 5;
    int c = (f & 31) * 4;
    const float* src;
    if (c < 64) {
      int nd = rowp[e0 + r];
      src = hbuf + (size_t)nd * 64 + c;
    } else {
      src = ea + (size_t)(e0 + r) * 64 + (c - 64);
    }
    float4 v = *(const float4*)src;
    u32 p0 = (u32)f2bf(v.x) | ((u32)f2bf(v.y) << 16);
    u32 p1 = (u32)f2bf(v.z) | ((u32)f2bf(v.w) << 16);
    u32* dst = (u32*)&xin[r * 136 + c];
    dst[0] = p0;
    dst[1] = p1;
  }
  __syncthreads();

  f32x4 zero = {0.f, 0.f, 0.f, 0.f};
  f32x4 acc1[2][4];
#pragma unroll
  for (int ni = 0; ni < 2; ni++)
#pragma unroll
    for (int mi = 0; mi < 4; mi++) acc1[ni][mi] = zero;
#pragma unroll
  for (int ki = 0; ki < 4; ki++) {
#pragma unroll
    for (int mi = 0; mi < 4; mi++) {
      bf16x8 A = *(const bf16x8*)&xin[(mi * 16 + m16) * 136 + ki * 32 + quad * 8];
      acc1[0][mi] = __builtin_amdgcn_mfma_f32_16x16x32_bf16(A, B1[0][ki], acc1[0][mi], 0, 0, 0);
      acc1[1][mi] = __builtin_amdgcn_mfma_f32_16x16x32_bf16(A, B1[1][ki], acc1[1][mi], 0, 0, 0);
    }
  }
  float b1v0 = b1[wave * 32 + m16];
  float b1v1 = b1[wave * 32 + 16 + m16];
#pragma unroll
  for (int mi = 0; mi < 4; mi++) {
#pragma unroll
    for (int reg = 0; reg < 4; reg++) {
      int r = mi * 16 + quad * 4 + reg;
      hid[r * 136 + wave * 32 + m16]      = f2bf(fmaxf(acc1[0][mi][reg] + b1v0, 0.f));
      hid[r * 136 + wave * 32 + 16 + m16] = f2bf(fmaxf(acc1[1][mi][reg] + b1v1, 0.f));
    }
  }
  __syncthreads();

  f32x4 acc2[4];
#pragma unroll
  for (int mi = 0; mi < 4; mi++) acc2[mi] = zero;
#pragma unroll
  for (int ki = 0; ki < 4; ki++) {
#pragma unroll
    for (int mi = 0; mi < 4; mi++) {
      bf16x8 A = *(const bf16x8*)&hid[(mi * 16 + m16) * 136 + ki * 32 + quad * 8];
      acc2[mi] = __builtin_amdgcn_mfma_f32_16x16x32_bf16(A, B2[ki], acc2[mi], 0, 0, 0);
    }
  }
  float b2v = b2[wave * 16 + m16];
#pragma unroll
  for (int mi = 0; mi < 4; mi++) {
#pragma unroll
    for (int reg = 0; reg < 4; reg++) {
      int r = mi * 16 + quad * 4 + reg;
      ea[(size_t)(e0 + r) * 64 + wave * 16 + m16] = acc2[mi][reg] + b2v;
    }
  }
  int g0 = ebatch[e0], g1 = ebatch[e0 + 63];
  int colo = wave * 16 + m16;
  if (g0 == g1) {
    float s = 0.f;
#pragma unroll
    for (int mi = 0; mi < 4; mi++)
#pragma unroll
      for (int reg = 0; reg < 4; reg++) s += acc2[mi][reg] + b2v;
    s += __shfl_xor(s, 16);
    s += __shfl_xor(s, 32);
    if (quad == 0) atomicAdd(&gacc[g0 * 256 + loff + colo], s);
  } else {
#pragma unroll
    for (int mi = 0; mi < 4; mi++)
#pragma unroll
      for (int reg = 0; reg < 4; reg++) {
        int r = mi * 16 + quad * 4 + reg;
        atomicAdd(&gacc[ebatch[e0 + r] * 256 + loff + colo], acc2[mi][reg] + b2v);
      }
  }
}

// ---------- finalize: means (acc already in output layout), head, f32 out ----------
__global__ __launch_bounds__(256) void finalize_k(
    const float* gn_acc, const float* ge_acc,
    const int* cnt_n, const int* cnt_e,
    const float* Wo1, const float* bo1,
    const float* Wo2, const float* bo2,
    const float* Wo3, const float* bo3,
    float* out) {
  __shared__ float attr[16][512];
  __shared__ float o1[16][128];
  __shared__ float o2[16][128];
  int t = threadIdx.x;
  for (int i = t; i < 4096; i += 256) {
    int g = i >> 8, c = i & 255;
    float vn = gn_acc[i] / (float)max(cnt_n[g], 1);
    float ve = ge_acc[i] / (float)max(cnt_e[g], 1);
    out[i] = vn;
    out[4096 + i] = ve;
    attr[g][c] = vn;
    attr[g][256 + c] = ve;
  }
  __syncthreads();
  {
    int j = t & 127, gh = t >> 7;
    float a[8];
#pragma unroll
    for (int q = 0; q < 8; q++) a[q] = bo1[j];
    for (int k = 0; k < 512; k++) {
      float w = Wo1[k * 128 + j];
#pragma unroll
      for (int q = 0; q < 8; q++) a[q] = fmaf(attr[gh * 8 + q][k], w, a[q]);
    }
#pragma unroll
    for (int q = 0; q < 8; q++) o1[gh * 8 + q][j] = fmaxf(a[q], 0.f);
  }
  __syncthreads();
  {
    int j = t & 127, gh = t >> 7;
    float a[8];
#pragma unroll
    for (int q = 0; q < 8; q++) a[q] = bo2[j];
    for (int k = 0; k < 128; k++) {
      float w = Wo2[k * 128 + j];
#pragma unroll
      for (int q = 0; q < 8; q++) a[q] = fmaf(o1[gh * 8 + q][k], w, a[q]);
    }
#pragma unroll
    for (int q = 0; q < 8; q++) o2[gh * 8 + q][j] = fmaxf(a[q], 0.f);
  }
  __syncthreads();
  {
    int j = t & 31, gb = t >> 5;
#pragma unroll
    for (int q = 0; q < 2; q++) {
      int g = gb * 2 + q;
      float a = bo3[j];
      for (int k = 0; k < 128; k++) a = fmaf(o2[g][k], Wo3[k * 32 + j], a);
      out[8192 + g * 32 + j] = a;
    }
  }
}

extern "C" void kernel_launch(void* const* d_in, const int* in_sizes, int n_in,
                              void* d_out, int out_size, void* d_ws, size_t ws_size,
                              hipStream_t stream) {
  float* ea = (float*)d_in[1];               // [NE,64] f32
  const int* edge_index = (const int*)d_in[3];
  const int* row = edge_index;
  const int* col = edge_index + NE;
  const int* batch = (const int*)d_in[4];
  const int* ebatch = (const int*)d_in[5];
  const float* W1s = (const float*)d_in[6];  // [3,128,128]
  const float* b1s = (const float*)d_in[7];  // [3,128]
  const float* W2s = (const float*)d_in[8];  // [3,128,64]
  const float* b2s = (const float*)d_in[9];  // [3,64]
  const float* Wo1 = (const float*)d_in[10];
  const float* bo1 = (const float*)d_in[11];
  const float* Wo2 = (const float*)d_in[12];
  const float* bo2 = (const float*)d_in[13];
  const float* Wo3 = (const float*)d_in[14];
  const float* bo3 = (const float*)d_in[15];

  char* p = (char*)d_ws;
  auto alloc = [&](size_t b) { char* r = p; p += (b + 255) & ~(size_t)255; return r; };
  // ---- zero region (one memset) ----
  int* deg = (int*)alloc(NN * 4);
  int* cursor = (int*)alloc(NN * 4);
  int* cnt_n = (int*)alloc(64);
  int* cnt_e = (int*)alloc(64);
  float* gn_acc = (float*)alloc(NGR * 256 * 4);
  float* ge_acc = (float*)alloc(NGR * 256 * 4);
  size_t zbytes = (size_t)(p - (char*)d_ws);
  // ---- non-zeroed ----
  int* csr_off = (int*)alloc((NN + 1) * 4);
  int* csr_eid = (int*)alloc((size_t)NE * 4);
  int* pos = (int*)alloc((size_t)NE * 4);
  int* rowsrt = (int*)alloc((size_t)NE * 4);
  int* ebs = (int*)alloc((size_t)NE * 4);
  float* hbuf = (float*)alloc((size_t)NN * 64 * 4);   // f32 fallback / bf16 CSR path
  u16* W1T = (u16*)alloc(3 * 128 * 128 * 2);
  u16* W2T = (u16*)alloc(3 * 64 * 128 * 2);
  int* eoff = (int*)alloc((NGR + 1) * 4);
  // esrt: CSR-permuted edge rows, BF16 (102MB) — only if workspace allows
  u16* esrt = nullptr;
  {
    size_t used = (size_t)(p - (char*)d_ws);
    size_t need = (size_t)NE * 64 * 2 + 512;
    if (ws_size >= used + need) esrt = (u16*)alloc((size_t)NE * 64 * 2);
  }

  hipMemsetAsync(d_ws, 0, zbytes, stream);

  prep_w_k<<<(3 * 128 * 128 + 3 * 128 * 64 + 255) / 256, 256, 0, stream>>>(W1s, W2s, W1T, W2T);
  hist_deg<<<(NE + 255) / 256, 256, 0, stream>>>(col, deg);
  count_graphs<<<1, 64, 0, stream>>>(batch, ebatch, cnt_n, cnt_e, eoff);
  scan_deg<<<1, 256, 0, stream>>>(deg, csr_off);
  fill_csr<<<(NE + 255) / 256, 256, 0, stream>>>(col, row, ebatch, csr_off, cursor,
                                                 csr_eid, pos, rowsrt, ebs);

  if (esrt) {
    // ---- CSR-native bf16 path ----
    u16* hbuf_b = (u16*)hbuf;
    pool_perm_k<<<2048, 256, 0, stream>>>(ea, eoff, pos, esrt, ge_acc, 0);
    gather_seq_k<<<2048, 256, 0, stream>>>(esrt, csr_off, batch, hbuf_b, gn_acc, 0, 1);
    for (int l = 0; l < 3; l++) {
      mlp_csr_k<<<2048, 256, 0, stream>>>(hbuf_b, esrt, rowsrt, ebs,
          W1T + l * 16384, b1s + l * 128, W2T + l * 8192, b2s + l * 64,
          ge_acc, (l + 1) * 64);
      gather_seq_k<<<2048, 256, 0, stream>>>(esrt, csr_off, batch, hbuf_b,
                                             gn_acc, (l + 1) * 64, l < 2 ? 1 : 0);
    }
  } else {
    // ---- fallback (round-2 proven f32): random gather via uniform eid ----
    pool_seg_k<<<2048, 256, 0, stream>>>(ea, eoff, ge_acc, 0);
    gather_k<<<2048, 256, 0, stream>>>(ea, csr_off, csr_eid, batch, hbuf, gn_acc, 0, 1);
    for (int l = 0; l < 3; l++) {
      mlp_fallback_k<<<NE / 64, 256, 0, stream>>>(hbuf, ea, row,
          W1T + l * 16384, b1s + l * 128, W2T + l * 8192, b2s + l * 64,
          ebatch, ge_acc, (l + 1) * 64);
      gather_k<<<2048, 256, 0, stream>>>(ea, csr_off, csr_eid, batch, hbuf,
                                         gn_acc, (l + 1) * 64, l < 2 ? 1 : 0);
    }
  }

  finalize_k<<<1, 256, 0, stream>>>(gn_acc, ge_acc, cnt_n, cnt_e,
      Wo1, bo1, Wo2, bo2, Wo3, bo3, (float*)d_out);
}